// Round 6
// baseline (838.113 us; speedup 1.0000x reference)
//
#include <hip/hip_runtime.h>
#include <stdint.h>

#define T_TOK 8192
#define DMODEL 1024
#define FDIM 4096
#define NEXP 8
#define NROWS 16384      // T_TOK * K
#define MAXT 80          // max 256-row tiles

typedef __bf16 bf16x8 __attribute__((ext_vector_type(8)));
typedef float f32x4 __attribute__((ext_vector_type(4)));
#define AS1 __attribute__((address_space(1)))
#define AS3 __attribute__((address_space(3)))

__device__ __forceinline__ unsigned short f2bf(float f) {
  union { float f; unsigned u; } v; v.f = f;
  unsigned r = v.u + 0x7fffu + ((v.u >> 16) & 1u);
  return (unsigned short)(r >> 16);
}
__device__ __forceinline__ float bflo(unsigned u) {
  union { unsigned u; float f; } v; v.u = u << 16; return v.f;
}
__device__ __forceinline__ float bfhi(unsigned u) {
  union { unsigned u; float f; } v; v.u = u & 0xffff0000u; return v.f;
}

// ---------------- gate: logits + top2 + softmax + expert counts ----------------
__global__ __launch_bounds__(256) void gate_kernel(
    const float* __restrict__ gx, const float* __restrict__ Wg,
    const float* __restrict__ bg, int* __restrict__ sel,
    float* __restrict__ wts, int* __restrict__ counts)
{
  int t = blockIdx.x * 4 + (threadIdx.x >> 6);
  int lane = threadIdx.x & 63;
  const float* row = gx + (size_t)t * DMODEL;
  float acc[NEXP];
#pragma unroll
  for (int e = 0; e < NEXP; ++e) acc[e] = 0.f;
  for (int d = lane; d < DMODEL; d += 64) {
    float x = row[d];
    const float* wgr = Wg + (size_t)d * NEXP;
#pragma unroll
    for (int e = 0; e < NEXP; ++e) acc[e] += x * wgr[e];
  }
#pragma unroll
  for (int off = 32; off > 0; off >>= 1) {
#pragma unroll
    for (int e = 0; e < NEXP; ++e) acc[e] += __shfl_down(acc[e], off);
  }
  if (lane == 0) {
    float lg[NEXP];
#pragma unroll
    for (int e = 0; e < NEXP; ++e) lg[e] = acc[e] + bg[e];
    int i1 = 0; float v1 = lg[0];
#pragma unroll
    for (int e = 1; e < NEXP; ++e) if (lg[e] > v1) { v1 = lg[e]; i1 = e; }
    int i2 = -1; float v2 = -3.4e38f;
#pragma unroll
    for (int e = 0; e < NEXP; ++e) if (e != i1 && lg[e] > v2) { v2 = lg[e]; i2 = e; }
    float ez = __expf(v2 - v1);           // v2 <= v1
    float s = 1.f / (1.f + ez);
    sel[t*2] = i1; sel[t*2+1] = i2;
    wts[t*2] = s;  wts[t*2+1] = ez * s;
    atomicAdd(&counts[i1], 1);
    atomicAdd(&counts[i2], 1);
  }
}

// ---------------- offsets + 256-row tile table (single thread) ----------------
__global__ void scan_build_kernel(const int* __restrict__ counts,
                                  int* __restrict__ offsets, int* __restrict__ ntiles,
                                  int* __restrict__ t_e, int* __restrict__ t_r,
                                  int* __restrict__ t_rend)
{
  if (threadIdx.x == 0 && blockIdx.x == 0) {
    int off = 0, n = 0;
    for (int e = 0; e < NEXP; ++e) {
      offsets[e] = off;
      int c = counts[e];
      for (int r = 0; r < c; r += 256) {
        t_e[n] = e; t_r[n] = off + r; t_rend[n] = off + c; ++n;
      }
      off += c;
    }
    offsets[NEXP] = off;
    *ntiles = n;
  }
}

// ---------------- scatter: compact per-expert token / slot lists --------------
__global__ __launch_bounds__(256) void scatter_kernel(
    const int* __restrict__ sel, int* __restrict__ cursors,
    const int* __restrict__ offsets, int* __restrict__ token_list,
    int* __restrict__ slot_list)
{
  int t = blockIdx.x * 256 + threadIdx.x;
  if (t >= T_TOK) return;
#pragma unroll
  for (int k = 0; k < 2; ++k) {
    int e = sel[t*2 + k];
    int pos = atomicAdd(&cursors[e], 1);
    int r = offsets[e] + pos;
    token_list[r] = t;
    slot_list[r] = t*2 + k;
  }
}

// ---------------- f32 -> bf16 (8 elems / thread) ------------------------------
__global__ __launch_bounds__(256) void cvt_bf16_kernel(
    const float* __restrict__ in, unsigned short* __restrict__ out, int n8)
{
  int i = blockIdx.x * 256 + threadIdx.x;
  if (i >= n8) return;
  const float4* in4 = (const float4*)in;
  float4 v0 = in4[(size_t)i*2], v1 = in4[(size_t)i*2 + 1];
  union { unsigned short u[8]; uint4 q; } r;
  r.u[0]=f2bf(v0.x); r.u[1]=f2bf(v0.y); r.u[2]=f2bf(v0.z); r.u[3]=f2bf(v0.w);
  r.u[4]=f2bf(v1.x); r.u[5]=f2bf(v1.y); r.u[6]=f2bf(v1.z); r.u[7]=f2bf(v1.w);
  ((uint4*)out)[i] = r.q;
}

// ---------------- [R][C] f32 -> [C][R] bf16 transpose (per expert) ------------
__global__ __launch_bounds__(256) void transpose_cvt_kernel(
    const float* __restrict__ in, unsigned short* __restrict__ out, int R, int C)
{
  __shared__ float tb[64][65];
  size_t ebase = (size_t)blockIdx.z * (size_t)R * (size_t)C;
  int r0 = blockIdx.y * 64, c0 = blockIdx.x * 64;
#pragma unroll
  for (int p = 0; p < 4; ++p) {
    int item = p * 256 + threadIdx.x;     // 1024 float4 items
    int r = item >> 4, c4 = (item & 15) * 4;
    float4 v = *(const float4*)&in[ebase + (size_t)(r0 + r) * C + (c0 + c4)];
    tb[r][c4+0] = v.x; tb[r][c4+1] = v.y; tb[r][c4+2] = v.z; tb[r][c4+3] = v.w;
  }
  __syncthreads();
#pragma unroll
  for (int p = 0; p < 2; ++p) {
    int item = p * 256 + threadIdx.x;      // 512 items: 64 c x 8 r-octs
    int c = item >> 3, r8 = (item & 7) * 8;
    union { unsigned short u[8]; uint4 q; } pk;
#pragma unroll
    for (int k = 0; k < 8; ++k) pk.u[k] = f2bf(tb[r8 + k][c]);
    *(uint4*)(out + ebase + (size_t)(c0 + c) * R + (r0 + r8)) = pk.q;
  }
}

// ---------------- grouped GEMM 256x256, BK=64, gray-code 4-phase --------------
// 8 waves (2M x 4N, wave tile 128x64). Register-resident fragments:
// aR = current A-half (8 frags), bR = BOTH B-halves (8 frags). Phase order
// (0,0)->(0,1)->(1,1)->(1,0); ds_reads per phase 12/4/8/0 = 24/K-tile
// (43.7 FLOP/LDS-byte vs R5's 21.8 -> LDS no longer the ceiling).
// Staging: 4 half-tile stages/K-tile into other buffer, counted vmcnt(2) at P0.
// G1: A rows gathered via token_list, gelu+bias epilogue -> H.
// !G1: A = H rows direct, raw epilogue scattered to ys via slot_list.
template<bool G1>
__global__ __launch_bounds__(512, 2) void gemm256_kernel(
    const unsigned short* __restrict__ A, const unsigned short* __restrict__ B,
    const float* __restrict__ b1, const int* __restrict__ token_list,
    const int* __restrict__ slot_list,
    const int* __restrict__ tile_e, const int* __restrict__ tile_r,
    const int* __restrict__ tile_rend, const int* __restrict__ ntiles,
    unsigned short* __restrict__ outp)
{
  constexpr int KDIM = G1 ? DMODEL : FDIM;   // K extent = A/B row stride
  constexpr int NKT  = KDIM / 64;
  constexpr int NOUT = G1 ? FDIM : DMODEL;   // output row width

  int bid = blockIdx.x;
  int nb, bt;
  if constexpr (G1) {                        // 16 nb-panels: pin 2 per XCD, bt-major
    int xcd = bid & 7, idx = bid >> 3;
    nb = xcd * 2 + (idx & 1);
    bt = idx >> 1;
  } else {                                   // 4 nb-panels, bt-major
    nb = bid & 3;
    bt = bid >> 2;
  }
  if (bt >= *ntiles) return;
  const int e = tile_e[bt], row0 = tile_r[bt], rend = tile_rend[bt];
  const int n0 = nb * 256;

  const int tid = threadIdx.x, lane = tid & 63, wave = tid >> 6;
  extern __shared__ __align__(16) char smem[];   // 131072 B

  // staging sources (granule-XOR pre-swizzle: LDS granule g of row m holds
  // global chunk g ^ (m&7); here lane's row = lr8, granule = g8)
  const int lr8 = lane >> 3, g8 = lane & 7, ch = g8 ^ lr8;
  unsigned aoffs[2][2], boffs[2][2];
#pragma unroll
  for (int h = 0; h < 2; ++h)
#pragma unroll
    for (int l = 0; l < 2; ++l) {
      int m = h*128 + wave*16 + l*8 + lr8;
      int row = row0 + m; if (row > NROWS - 1) row = NROWS - 1;
      int arow = G1 ? token_list[row] : row;
      aoffs[h][l] = (unsigned)arow * KDIM + ch*8;
      boffs[h][l] = (unsigned)(e * NOUT + n0 + m) * KDIM + ch*8;
    }

  auto stage_half = [&](int p, int ktn, int bsel) {
    const int kb = ktn * 64;
    char* base = smem + bsel * 65536;
    if (p < 2) {
#pragma unroll
      for (int l = 0; l < 2; ++l)
        __builtin_amdgcn_global_load_lds(
            (const AS1 void*)(A + aoffs[p][l] + kb),
            (AS3 void*)(base + ((p*128 + wave*16 + l*8) << 7)), 16, 0, 0);
    } else {
#pragma unroll
      for (int l = 0; l < 2; ++l)
        __builtin_amdgcn_global_load_lds(
            (const AS1 void*)(B + boffs[p-2][l] + kb),
            (AS3 void*)(base + 32768 + (((p-2)*128 + wave*16 + l*8) << 7)), 16, 0, 0);
    }
  };

  f32x4 acc[8][4] = {};
  bf16x8 aR[4][2];        // current A-half: 4 row-frags x 2 k-slices
  bf16x8 bR[2][2][2];     // both B-halves: [nh][jj][ks]
  const int wr = wave >> 2, wc = wave & 3;
  const int lm = lane & 15, lk = lane >> 4, l7 = lane & 7;
  const unsigned abase = (unsigned)(wr*128 + lm) * 128;
  const unsigned bbase = 32768u + (unsigned)(wc*64 + lm) * 128;
  const unsigned kx0 = (unsigned)((lk ^ l7) << 4);
  const unsigned kx1 = (unsigned)(((4 + lk) ^ l7) << 4);

  auto rdA = [&](const char* base, int mh) {
#pragma unroll
    for (int i = 0; i < 4; ++i) {
      const char* pA = base + abase + mh*8192 + i*2048;
      aR[i][0] = *(const bf16x8*)(pA + kx0);
      aR[i][1] = *(const bf16x8*)(pA + kx1);
    }
  };
  auto rdB = [&](const char* base, int nh) {
#pragma unroll
    for (int jj = 0; jj < 2; ++jj) {
      const char* pB = base + bbase + nh*4096 + jj*2048;
      bR[nh][jj][0] = *(const bf16x8*)(pB + kx0);
      bR[nh][jj][1] = *(const bf16x8*)(pB + kx1);
    }
  };
  auto mm = [&](int mh, int nh) {
    __builtin_amdgcn_s_setprio(1);
#pragma unroll
    for (int i = 0; i < 4; ++i)
#pragma unroll
      for (int jj = 0; jj < 2; ++jj) {
        acc[mh*4+i][nh*2+jj] = __builtin_amdgcn_mfma_f32_16x16x32_bf16(
            aR[i][0], bR[nh][jj][0], acc[mh*4+i][nh*2+jj], 0, 0, 0);
        acc[mh*4+i][nh*2+jj] = __builtin_amdgcn_mfma_f32_16x16x32_bf16(
            aR[i][1], bR[nh][jj][1], acc[mh*4+i][nh*2+jj], 0, 0, 0);
      }
    __builtin_amdgcn_s_setprio(0);
  };

  // prologue: stage all 4 halves of tile 0 into buf0
#pragma unroll
  for (int p = 0; p < 4; ++p) stage_half(p, 0, 0);

  for (int kt = 0; kt < NKT; ++kt) {
    const int b = kt & 1;
    const char* base = smem + b * 65536;
    const bool pre = (kt + 1 < NKT);
    // ---- P0: quad (0,0); reads A0 + B0 ----
    if (pre) {
      stage_half(0, kt + 1, b ^ 1);
      asm volatile("s_waitcnt vmcnt(2)" ::: "memory");   // prev tile's 8 done
    } else {
      asm volatile("s_waitcnt vmcnt(0)" ::: "memory");
    }
    __builtin_amdgcn_s_barrier();
    __builtin_amdgcn_sched_barrier(0);
    rdA(base, 0); rdB(base, 0);
    asm volatile("s_waitcnt lgkmcnt(0)" ::: "memory");
    __builtin_amdgcn_sched_barrier(0);
    mm(0, 0);
    __builtin_amdgcn_s_barrier();
    __builtin_amdgcn_sched_barrier(0);
    // ---- P1: quad (0,1); reads B1 ----
    rdB(base, 1);
    if (pre) stage_half(1, kt + 1, b ^ 1);
    __builtin_amdgcn_s_barrier();
    asm volatile("s_waitcnt lgkmcnt(0)" ::: "memory");
    __builtin_amdgcn_sched_barrier(0);
    mm(0, 1);
    __builtin_amdgcn_s_barrier();
    __builtin_amdgcn_sched_barrier(0);
    // ---- P2: quad (1,1); reads A1 ----
    rdA(base, 1);
    if (pre) stage_half(2, kt + 1, b ^ 1);
    __builtin_amdgcn_s_barrier();
    asm volatile("s_waitcnt lgkmcnt(0)" ::: "memory");
    __builtin_amdgcn_sched_barrier(0);
    mm(1, 1);
    __builtin_amdgcn_s_barrier();
    __builtin_amdgcn_sched_barrier(0);
    // ---- P3: quad (1,0); no reads (A1, B0 resident) ----
    if (pre) stage_half(3, kt + 1, b ^ 1);
    __builtin_amdgcn_s_barrier();
    __builtin_amdgcn_sched_barrier(0);
    mm(1, 0);
    __builtin_amdgcn_s_barrier();
    __builtin_amdgcn_sched_barrier(0);
  }

  asm volatile("" ::: "memory");
  float bias[4] = {};
  if constexpr (G1) {
#pragma unroll
    for (int j = 0; j < 4; ++j) bias[j] = b1[(size_t)e * FDIM + n0 + wc*64 + j*16 + lm];
  }

  // epilogue: 8 chunks of 32 rows; [gelu] -> f32 LDS (stride 260) -> bf16 x8
  float* eps = (float*)smem;
#pragma unroll
  for (int c = 0; c < 8; ++c) {
    __syncthreads();
    if (wr == (c >> 2)) {
#pragma unroll
      for (int ii = 0; ii < 2; ++ii) {
        const int mi = (c & 3) * 2 + ii;
#pragma unroll
        for (int j = 0; j < 4; ++j) {
#pragma unroll
          for (int r = 0; r < 4; ++r) {
            float v = acc[mi][j][r];
            if constexpr (G1) {
              v += bias[j];
              float z2 = 1.5957691216f * (v + 0.044715f * v * v * v);
              v = v / (1.f + __expf(-z2));
            }
            eps[(ii*16 + lk*4 + r) * 260 + wc*64 + j*16 + lm] = v;
          }
        }
      }
    }
    __syncthreads();
#pragma unroll
    for (int u = 0; u < 2; ++u) {
      int item = u * 512 + tid;               // 1024 items: 32 rows x 32 octs
      int lrow = item >> 5, c8 = (item & 31) * 8;
      int gr = row0 + c * 32 + lrow;
      if (gr < rend) {
        float4 v0 = *(const float4*)&eps[lrow * 260 + c8];
        float4 v1 = *(const float4*)&eps[lrow * 260 + c8 + 4];
        union { unsigned short u[8]; uint4 q; } pk;
        pk.u[0]=f2bf(v0.x); pk.u[1]=f2bf(v0.y); pk.u[2]=f2bf(v0.z); pk.u[3]=f2bf(v0.w);
        pk.u[4]=f2bf(v1.x); pk.u[5]=f2bf(v1.y); pk.u[6]=f2bf(v1.z); pk.u[7]=f2bf(v1.w);
        size_t orow;
        if constexpr (G1) orow = (size_t)gr * FDIM;
        else              orow = (size_t)slot_list[gr] * DMODEL;
        *(uint4*)(outp + orow + n0 + c8) = pk.q;
      }
    }
  }
}

// ---------------- combine: out = sum_k w_k*(y_k + b2[e_k]) --------------------
__global__ __launch_bounds__(256) void combine_kernel(
    const unsigned short* __restrict__ ys, const float* __restrict__ wts,
    const int* __restrict__ sel, const float* __restrict__ b2,
    float* __restrict__ out)
{
  int i = blockIdx.x * 256 + threadIdx.x;   // over T*D/8
  int t = i >> 7, d8 = i & 127;
  float w0 = wts[t*2], w1 = wts[t*2 + 1];
  int e0 = sel[t*2], e1 = sel[t*2 + 1];
  const uint4* ys4 = (const uint4*)ys;
  uint4 ya = ys4[(size_t)(t*2) * 128 + d8];
  uint4 yb = ys4[(size_t)(t*2 + 1) * 128 + d8];
  const float4* b24 = (const float4*)b2;
  float4 c0a = b24[e0*256 + d8*2], c0b = b24[e0*256 + d8*2 + 1];
  float4 c1a = b24[e1*256 + d8*2], c1b = b24[e1*256 + d8*2 + 1];
  float4 o0, o1;
  o0.x = w0*(bflo(ya.x)+c0a.x) + w1*(bflo(yb.x)+c1a.x);
  o0.y = w0*(bfhi(ya.x)+c0a.y) + w1*(bfhi(yb.x)+c1a.y);
  o0.z = w0*(bflo(ya.y)+c0a.z) + w1*(bflo(yb.y)+c1a.z);
  o0.w = w0*(bfhi(ya.y)+c0a.w) + w1*(bfhi(yb.y)+c1a.w);
  o1.x = w0*(bflo(ya.z)+c0b.x) + w1*(bflo(yb.z)+c1b.x);
  o1.y = w0*(bfhi(ya.z)+c0b.y) + w1*(bfhi(yb.z)+c1b.y);
  o1.z = w0*(bflo(ya.w)+c0b.z) + w1*(bflo(yb.w)+c1b.z);
  o1.w = w0*(bfhi(ya.w)+c0b.w) + w1*(bfhi(yb.w)+c1b.w);
  float4* out4 = (float4*)out;
  out4[(size_t)t * 256 + d8*2]     = o0;
  out4[(size_t)t * 256 + d8*2 + 1] = o1;
}

// ---------------- host ---------------------------------------------------------
extern "C" void kernel_launch(void* const* d_in, const int* in_sizes, int n_in,
                              void* d_out, int out_size, void* d_ws, size_t ws_size,
                              hipStream_t stream)
{
  const float* gate_inputs = (const float*)d_in[0];
  const float* inputs      = (const float*)d_in[1];
  const float* Wg          = (const float*)d_in[2];
  const float* bg          = (const float*)d_in[3];
  const float* w1          = (const float*)d_in[4];
  const float* b1          = (const float*)d_in[5];
  const float* w2          = (const float*)d_in[6];
  const float* b2          = (const float*)d_in[7];
  float* out = (float*)d_out;

  char* ws = (char*)d_ws;
  size_t o = 0;
  auto carve = [&](size_t bytes) { void* p = ws + o; o += (bytes + 255) & ~(size_t)255; return p; };
  unsigned short* Xb  = (unsigned short*)carve((size_t)T_TOK * DMODEL * 2);
  unsigned short* W1T = (unsigned short*)carve((size_t)NEXP * FDIM * DMODEL * 2);
  unsigned short* W2T = (unsigned short*)carve((size_t)NEXP * DMODEL * FDIM * 2);
  unsigned short* H   = (unsigned short*)carve((size_t)NROWS * FDIM * 2);
  unsigned short* ys  = (unsigned short*)carve((size_t)NROWS * DMODEL * 2);
  int*   sel          = (int*)carve((size_t)NROWS * 4);
  float* wts          = (float*)carve((size_t)NROWS * 4);
  int*   token_list   = (int*)carve((size_t)(NROWS + 256) * 4);
  int*   slot_list    = (int*)carve((size_t)(NROWS + 256) * 4);
  int*   ctrl         = (int*)carve(4096);
  int* counts  = ctrl;            // 8
  int* cursors = ctrl + 8;        // 8
  int* offsets = ctrl + 16;       // 9
  int* ntiles  = ctrl + 28;       // 1
  int* t_e     = ctrl + 32;
  int* t_r     = ctrl + 32 + MAXT;
  int* t_rend  = ctrl + 32 + 2 * MAXT;

  hipMemsetAsync(counts, 0, 64, stream);  // counts + cursors

  gate_kernel<<<T_TOK / 4, 256, 0, stream>>>(gate_inputs, Wg, bg, sel, wts, counts);
  scan_build_kernel<<<1, 64, 0, stream>>>(counts, offsets, ntiles, t_e, t_r, t_rend);
  scatter_kernel<<<T_TOK / 256, 256, 0, stream>>>(sel, cursors, offsets, token_list, slot_list);
  cvt_bf16_kernel<<<(T_TOK * DMODEL / 8) / 256, 256, 0, stream>>>(inputs, Xb, T_TOK * DMODEL / 8);
  transpose_cvt_kernel<<<dim3(FDIM / 64, DMODEL / 64, NEXP), 256, 0, stream>>>(w1, W1T, DMODEL, FDIM);
  transpose_cvt_kernel<<<dim3(DMODEL / 64, FDIM / 64, NEXP), 256, 0, stream>>>(w2, W2T, FDIM, DMODEL);

  hipFuncSetAttribute((const void*)gemm256_kernel<true>,
                      hipFuncAttributeMaxDynamicSharedMemorySize, 131072);
  hipFuncSetAttribute((const void*)gemm256_kernel<false>,
                      hipFuncAttributeMaxDynamicSharedMemorySize, 131072);
  // gemm1: H = gelu(X@W1+b1). grid = 8 xcd * (2 nb-sub * 80 bt)
  gemm256_kernel<true><<<8 * 2 * MAXT, 512, 131072, stream>>>(
      Xb, W1T, b1, token_list, nullptr, t_e, t_r, t_rend, ntiles, H);
  // gemm2: ys = H@W2 scatter. grid = 4 nb * 80 bt
  gemm256_kernel<false><<<4 * MAXT, 512, 131072, stream>>>(
      H, W2T, nullptr, nullptr, slot_list, t_e, t_r, t_rend, ntiles, ys);
  combine_kernel<<<(T_TOK * DMODEL / 8) / 256, 256, 0, stream>>>(ys, wts, sel, b2, out);
}

// Round 7
// 814.258 us; speedup vs baseline: 1.0293x; 1.0293x over previous
//
#include <hip/hip_runtime.h>
#include <stdint.h>

#define T_TOK 8192
#define DMODEL 1024
#define FDIM 4096
#define NEXP 8
#define NROWS 16384      // T_TOK * K
#define MAXT 80          // max 256-row tiles

typedef __bf16 bf16x8 __attribute__((ext_vector_type(8)));
typedef float f32x4 __attribute__((ext_vector_type(4)));
#define AS1 __attribute__((address_space(1)))
#define AS3 __attribute__((address_space(3)))

__device__ __forceinline__ unsigned short f2bf(float f) {
  union { float f; unsigned u; } v; v.f = f;
  unsigned r = v.u + 0x7fffu + ((v.u >> 16) & 1u);
  return (unsigned short)(r >> 16);
}
__device__ __forceinline__ float bflo(unsigned u) {
  union { unsigned u; float f; } v; v.u = u << 16; return v.f;
}
__device__ __forceinline__ float bfhi(unsigned u) {
  union { unsigned u; float f; } v; v.u = u & 0xffff0000u; return v.f;
}

// ---------------- gate: logits + top2 + softmax + expert counts ----------------
__global__ __launch_bounds__(256) void gate_kernel(
    const float* __restrict__ gx, const float* __restrict__ Wg,
    const float* __restrict__ bg, int* __restrict__ sel,
    float* __restrict__ wts, int* __restrict__ counts)
{
  int t = blockIdx.x * 4 + (threadIdx.x >> 6);
  int lane = threadIdx.x & 63;
  const float* row = gx + (size_t)t * DMODEL;
  float acc[NEXP];
#pragma unroll
  for (int e = 0; e < NEXP; ++e) acc[e] = 0.f;
  for (int d = lane; d < DMODEL; d += 64) {
    float x = row[d];
    const float* wgr = Wg + (size_t)d * NEXP;
#pragma unroll
    for (int e = 0; e < NEXP; ++e) acc[e] += x * wgr[e];
  }
#pragma unroll
  for (int off = 32; off > 0; off >>= 1) {
#pragma unroll
    for (int e = 0; e < NEXP; ++e) acc[e] += __shfl_down(acc[e], off);
  }
  if (lane == 0) {
    float lg[NEXP];
#pragma unroll
    for (int e = 0; e < NEXP; ++e) lg[e] = acc[e] + bg[e];
    int i1 = 0; float v1 = lg[0];
#pragma unroll
    for (int e = 1; e < NEXP; ++e) if (lg[e] > v1) { v1 = lg[e]; i1 = e; }
    int i2 = -1; float v2 = -3.4e38f;
#pragma unroll
    for (int e = 0; e < NEXP; ++e) if (e != i1 && lg[e] > v2) { v2 = lg[e]; i2 = e; }
    float ez = __expf(v2 - v1);           // v2 <= v1
    float s = 1.f / (1.f + ez);
    sel[t*2] = i1; sel[t*2+1] = i2;
    wts[t*2] = s;  wts[t*2+1] = ez * s;
    atomicAdd(&counts[i1], 1);
    atomicAdd(&counts[i2], 1);
  }
}

// ---------------- offsets + 256-row tile table (single thread) ----------------
__global__ void scan_build_kernel(const int* __restrict__ counts,
                                  int* __restrict__ offsets, int* __restrict__ ntiles,
                                  int* __restrict__ t_e, int* __restrict__ t_r,
                                  int* __restrict__ t_rend)
{
  if (threadIdx.x == 0 && blockIdx.x == 0) {
    int off = 0, n = 0;
    for (int e = 0; e < NEXP; ++e) {
      offsets[e] = off;
      int c = counts[e];
      for (int r = 0; r < c; r += 256) {
        t_e[n] = e; t_r[n] = off + r; t_rend[n] = off + c; ++n;
      }
      off += c;
    }
    offsets[NEXP] = off;
    *ntiles = n;
  }
}

// ---------------- scatter: compact per-expert token / slot lists --------------
__global__ __launch_bounds__(256) void scatter_kernel(
    const int* __restrict__ sel, int* __restrict__ cursors,
    const int* __restrict__ offsets, int* __restrict__ token_list,
    int* __restrict__ slot_list)
{
  int t = blockIdx.x * 256 + threadIdx.x;
  if (t >= T_TOK) return;
#pragma unroll
  for (int k = 0; k < 2; ++k) {
    int e = sel[t*2 + k];
    int pos = atomicAdd(&cursors[e], 1);
    int r = offsets[e] + pos;
    token_list[r] = t;
    slot_list[r] = t*2 + k;
  }
}

// ---------------- f32 -> bf16 (8 elems / thread) ------------------------------
__global__ __launch_bounds__(256) void cvt_bf16_kernel(
    const float* __restrict__ in, unsigned short* __restrict__ out, int n8)
{
  int i = blockIdx.x * 256 + threadIdx.x;
  if (i >= n8) return;
  const float4* in4 = (const float4*)in;
  float4 v0 = in4[(size_t)i*2], v1 = in4[(size_t)i*2 + 1];
  union { unsigned short u[8]; uint4 q; } r;
  r.u[0]=f2bf(v0.x); r.u[1]=f2bf(v0.y); r.u[2]=f2bf(v0.z); r.u[3]=f2bf(v0.w);
  r.u[4]=f2bf(v1.x); r.u[5]=f2bf(v1.y); r.u[6]=f2bf(v1.z); r.u[7]=f2bf(v1.w);
  ((uint4*)out)[i] = r.q;
}

// ---------------- [R][C] f32 -> [C][R] bf16 transpose (per expert) ------------
__global__ __launch_bounds__(256) void transpose_cvt_kernel(
    const float* __restrict__ in, unsigned short* __restrict__ out, int R, int C)
{
  __shared__ float tb[64][65];
  size_t ebase = (size_t)blockIdx.z * (size_t)R * (size_t)C;
  int r0 = blockIdx.y * 64, c0 = blockIdx.x * 64;
#pragma unroll
  for (int p = 0; p < 4; ++p) {
    int item = p * 256 + threadIdx.x;     // 1024 float4 items
    int r = item >> 4, c4 = (item & 15) * 4;
    float4 v = *(const float4*)&in[ebase + (size_t)(r0 + r) * C + (c0 + c4)];
    tb[r][c4+0] = v.x; tb[r][c4+1] = v.y; tb[r][c4+2] = v.z; tb[r][c4+3] = v.w;
  }
  __syncthreads();
#pragma unroll
  for (int p = 0; p < 2; ++p) {
    int item = p * 256 + threadIdx.x;      // 512 items: 64 c x 8 r-octs
    int c = item >> 3, r8 = (item & 7) * 8;
    union { unsigned short u[8]; uint4 q; } pk;
#pragma unroll
    for (int k = 0; k < 8; ++k) pk.u[k] = f2bf(tb[r8 + k][c]);
    *(uint4*)(out + ebase + (size_t)(c0 + c) * R + (r0 + r8)) = pk.q;
  }
}

// ---------------- grouped GEMM 256x256, BK=64, barrier-minimal ----------------
// 8 waves (2M x 4N, wave tile 128x64), 128KB dbuf LDS, gray-code register
// residency (aR current A-half, bR both B-halves). ONE sync point per K-tile:
// lgkm(0)+sched_barrier [rule 18] + vmcnt(0)+s_barrier. All 4 next-tile
// stage-halves issued at TILE TOP (early-issue/late-wait: vmcnt(0) at tile end
// waits loads issued a full tile earlier). No intra-tile barriers: waves
// free-run, compiler inserts fine-grained lgkmcnt before each MFMA use.
template<bool G1>
__global__ __launch_bounds__(512, 2) void gemm256_kernel(
    const unsigned short* __restrict__ A, const unsigned short* __restrict__ B,
    const float* __restrict__ b1, const int* __restrict__ token_list,
    const int* __restrict__ slot_list,
    const int* __restrict__ tile_e, const int* __restrict__ tile_r,
    const int* __restrict__ tile_rend, const int* __restrict__ ntiles,
    unsigned short* __restrict__ outp)
{
  constexpr int KDIM = G1 ? DMODEL : FDIM;   // K extent = A/B row stride
  constexpr int NKT  = KDIM / 64;
  constexpr int NOUT = G1 ? FDIM : DMODEL;   // output row width

  int bid = blockIdx.x;
  int nb, bt;
  if constexpr (G1) {                        // 16 nb-panels: pin 2 per XCD, bt-major
    int xcd = bid & 7, idx = bid >> 3;
    nb = xcd * 2 + (idx & 1);
    bt = idx >> 1;
  } else {                                   // 4 nb-panels, bt-major
    nb = bid & 3;
    bt = bid >> 2;
  }
  if (bt >= *ntiles) return;
  const int e = tile_e[bt], row0 = tile_r[bt], rend = tile_rend[bt];
  const int n0 = nb * 256;

  const int tid = threadIdx.x, lane = tid & 63, wave = tid >> 6;
  extern __shared__ __align__(16) char smem[];   // 131072 B

  // staging sources (granule-XOR pre-swizzle: LDS granule g of row m holds
  // global chunk g ^ (m&7); here lane's row = lr8, granule = g8)
  const int lr8 = lane >> 3, g8 = lane & 7, ch = g8 ^ lr8;
  unsigned aoffs[2][2], boffs[2][2];
#pragma unroll
  for (int h = 0; h < 2; ++h)
#pragma unroll
    for (int l = 0; l < 2; ++l) {
      int m = h*128 + wave*16 + l*8 + lr8;
      int row = row0 + m; if (row > NROWS - 1) row = NROWS - 1;
      int arow = G1 ? token_list[row] : row;
      aoffs[h][l] = (unsigned)arow * KDIM + ch*8;
      boffs[h][l] = (unsigned)(e * NOUT + n0 + m) * KDIM + ch*8;
    }

  auto stage_half = [&](int p, int ktn, int bsel) {
    const int kb = ktn * 64;
    char* base = smem + bsel * 65536;
    if (p < 2) {
#pragma unroll
      for (int l = 0; l < 2; ++l)
        __builtin_amdgcn_global_load_lds(
            (const AS1 void*)(A + aoffs[p][l] + kb),
            (AS3 void*)(base + ((p*128 + wave*16 + l*8) << 7)), 16, 0, 0);
    } else {
#pragma unroll
      for (int l = 0; l < 2; ++l)
        __builtin_amdgcn_global_load_lds(
            (const AS1 void*)(B + boffs[p-2][l] + kb),
            (AS3 void*)(base + 32768 + (((p-2)*128 + wave*16 + l*8) << 7)), 16, 0, 0);
    }
  };

  f32x4 acc[8][4] = {};
  bf16x8 aR[4][2];        // current A-half: 4 row-frags x 2 k-slices
  bf16x8 bR[2][2][2];     // both B-halves: [nh][jj][ks]
  const int wr = wave >> 2, wc = wave & 3;
  const int lm = lane & 15, lk = lane >> 4, l7 = lane & 7;
  const unsigned abase = (unsigned)(wr*128 + lm) * 128;
  const unsigned bbase = 32768u + (unsigned)(wc*64 + lm) * 128;
  const unsigned kx0 = (unsigned)((lk ^ l7) << 4);
  const unsigned kx1 = (unsigned)(((4 + lk) ^ l7) << 4);

  auto rdA = [&](const char* base, int mh) {
#pragma unroll
    for (int i = 0; i < 4; ++i) {
      const char* pA = base + abase + mh*8192 + i*2048;
      aR[i][0] = *(const bf16x8*)(pA + kx0);
      aR[i][1] = *(const bf16x8*)(pA + kx1);
    }
  };
  auto rdB = [&](const char* base, int nh) {
#pragma unroll
    for (int jj = 0; jj < 2; ++jj) {
      const char* pB = base + bbase + nh*4096 + jj*2048;
      bR[nh][jj][0] = *(const bf16x8*)(pB + kx0);
      bR[nh][jj][1] = *(const bf16x8*)(pB + kx1);
    }
  };
  auto mm = [&](int mh, int nh) {
#pragma unroll
    for (int i = 0; i < 4; ++i)
#pragma unroll
      for (int jj = 0; jj < 2; ++jj) {
        acc[mh*4+i][nh*2+jj] = __builtin_amdgcn_mfma_f32_16x16x32_bf16(
            aR[i][0], bR[nh][jj][0], acc[mh*4+i][nh*2+jj], 0, 0, 0);
        acc[mh*4+i][nh*2+jj] = __builtin_amdgcn_mfma_f32_16x16x32_bf16(
            aR[i][1], bR[nh][jj][1], acc[mh*4+i][nh*2+jj], 0, 0, 0);
      }
  };

  // prologue: stage all 4 halves of tile 0 into buf0, confirm
#pragma unroll
  for (int p = 0; p < 4; ++p) stage_half(p, 0, 0);
  asm volatile("s_waitcnt vmcnt(0)" ::: "memory");
  __builtin_amdgcn_s_barrier();
  __builtin_amdgcn_sched_barrier(0);

  for (int kt = 0; kt < NKT; ++kt) {
    const int b = kt & 1;
    const char* base = smem + b * 65536;
    // issue ALL next-tile stages at tile top (budget = full tile until vmcnt)
    if (kt + 1 < NKT) {
#pragma unroll
      for (int p = 0; p < 4; ++p) stage_half(p, kt + 1, b ^ 1);
    }
    // gray-code quadrants, compiler-scheduled (no barriers, no manual lgkm)
    rdA(base, 0); rdB(base, 0);
    mm(0, 0);
    rdB(base, 1);
    mm(0, 1);
    rdA(base, 1);
    mm(1, 1);
    mm(1, 0);
    // single per-tile sync: reads landed, stages landed, all waves past
    asm volatile("s_waitcnt lgkmcnt(0)" ::: "memory");
    __builtin_amdgcn_sched_barrier(0);
    asm volatile("s_waitcnt vmcnt(0)" ::: "memory");
    __builtin_amdgcn_s_barrier();
    __builtin_amdgcn_sched_barrier(0);
  }

  asm volatile("" ::: "memory");
  float bias[4] = {};
  if constexpr (G1) {
#pragma unroll
    for (int j = 0; j < 4; ++j) bias[j] = b1[(size_t)e * FDIM + n0 + wc*64 + j*16 + lm];
  }

  // epilogue: 8 chunks of 32 rows; [gelu] -> f32 LDS (stride 260) -> bf16 x8
  float* eps = (float*)smem;
#pragma unroll
  for (int c = 0; c < 8; ++c) {
    __syncthreads();
    if (wr == (c >> 2)) {
#pragma unroll
      for (int ii = 0; ii < 2; ++ii) {
        const int mi = (c & 3) * 2 + ii;
#pragma unroll
        for (int j = 0; j < 4; ++j) {
#pragma unroll
          for (int r = 0; r < 4; ++r) {
            float v = acc[mi][j][r];
            if constexpr (G1) {
              v += bias[j];
              float z2 = 1.5957691216f * (v + 0.044715f * v * v * v);
              v = v / (1.f + __expf(-z2));
            }
            eps[(ii*16 + lk*4 + r) * 260 + wc*64 + j*16 + lm] = v;
          }
        }
      }
    }
    __syncthreads();
#pragma unroll
    for (int u = 0; u < 2; ++u) {
      int item = u * 512 + tid;               // 1024 items: 32 rows x 32 octs
      int lrow = item >> 5, c8 = (item & 31) * 8;
      int gr = row0 + c * 32 + lrow;
      if (gr < rend) {
        float4 v0 = *(const float4*)&eps[lrow * 260 + c8];
        float4 v1 = *(const float4*)&eps[lrow * 260 + c8 + 4];
        union { unsigned short u[8]; uint4 q; } pk;
        pk.u[0]=f2bf(v0.x); pk.u[1]=f2bf(v0.y); pk.u[2]=f2bf(v0.z); pk.u[3]=f2bf(v0.w);
        pk.u[4]=f2bf(v1.x); pk.u[5]=f2bf(v1.y); pk.u[6]=f2bf(v1.z); pk.u[7]=f2bf(v1.w);
        size_t orow;
        if constexpr (G1) orow = (size_t)gr * FDIM;
        else              orow = (size_t)slot_list[gr] * DMODEL;
        *(uint4*)(outp + orow + n0 + c8) = pk.q;
      }
    }
  }
}

// ---------------- combine: out = sum_k w_k*(y_k + b2[e_k]) --------------------
__global__ __launch_bounds__(256) void combine_kernel(
    const unsigned short* __restrict__ ys, const float* __restrict__ wts,
    const int* __restrict__ sel, const float* __restrict__ b2,
    float* __restrict__ out)
{
  int i = blockIdx.x * 256 + threadIdx.x;   // over T*D/8
  int t = i >> 7, d8 = i & 127;
  float w0 = wts[t*2], w1 = wts[t*2 + 1];
  int e0 = sel[t*2], e1 = sel[t*2 + 1];
  const uint4* ys4 = (const uint4*)ys;
  uint4 ya = ys4[(size_t)(t*2) * 128 + d8];
  uint4 yb = ys4[(size_t)(t*2 + 1) * 128 + d8];
  const float4* b24 = (const float4*)b2;
  float4 c0a = b24[e0*256 + d8*2], c0b = b24[e0*256 + d8*2 + 1];
  float4 c1a = b24[e1*256 + d8*2], c1b = b24[e1*256 + d8*2 + 1];
  float4 o0, o1;
  o0.x = w0*(bflo(ya.x)+c0a.x) + w1*(bflo(yb.x)+c1a.x);
  o0.y = w0*(bfhi(ya.x)+c0a.y) + w1*(bfhi(yb.x)+c1a.y);
  o0.z = w0*(bflo(ya.y)+c0a.z) + w1*(bflo(yb.y)+c1a.z);
  o0.w = w0*(bfhi(ya.y)+c0a.w) + w1*(bfhi(yb.y)+c1a.w);
  o1.x = w0*(bflo(ya.z)+c0b.x) + w1*(bflo(yb.z)+c1b.x);
  o1.y = w0*(bfhi(ya.z)+c0b.y) + w1*(bfhi(yb.z)+c1b.y);
  o1.z = w0*(bflo(ya.w)+c0b.z) + w1*(bflo(yb.w)+c1b.z);
  o1.w = w0*(bfhi(ya.w)+c0b.w) + w1*(bfhi(yb.w)+c1b.w);
  float4* out4 = (float4*)out;
  out4[(size_t)t * 256 + d8*2]     = o0;
  out4[(size_t)t * 256 + d8*2 + 1] = o1;
}

// ---------------- host ---------------------------------------------------------
extern "C" void kernel_launch(void* const* d_in, const int* in_sizes, int n_in,
                              void* d_out, int out_size, void* d_ws, size_t ws_size,
                              hipStream_t stream)
{
  const float* gate_inputs = (const float*)d_in[0];
  const float* inputs      = (const float*)d_in[1];
  const float* Wg          = (const float*)d_in[2];
  const float* bg          = (const float*)d_in[3];
  const float* w1          = (const float*)d_in[4];
  const float* b1          = (const float*)d_in[5];
  const float* w2          = (const float*)d_in[6];
  const float* b2          = (const float*)d_in[7];
  float* out = (float*)d_out;

  char* ws = (char*)d_ws;
  size_t o = 0;
  auto carve = [&](size_t bytes) { void* p = ws + o; o += (bytes + 255) & ~(size_t)255; return p; };
  unsigned short* Xb  = (unsigned short*)carve((size_t)T_TOK * DMODEL * 2);
  unsigned short* W1T = (unsigned short*)carve((size_t)NEXP * FDIM * DMODEL * 2);
  unsigned short* W2T = (unsigned short*)carve((size_t)NEXP * DMODEL * FDIM * 2);
  unsigned short* H   = (unsigned short*)carve((size_t)NROWS * FDIM * 2);
  unsigned short* ys  = (unsigned short*)carve((size_t)NROWS * DMODEL * 2);
  int*   sel          = (int*)carve((size_t)NROWS * 4);
  float* wts          = (float*)carve((size_t)NROWS * 4);
  int*   token_list   = (int*)carve((size_t)(NROWS + 256) * 4);
  int*   slot_list    = (int*)carve((size_t)(NROWS + 256) * 4);
  int*   ctrl         = (int*)carve(4096);
  int* counts  = ctrl;            // 8
  int* cursors = ctrl + 8;        // 8
  int* offsets = ctrl + 16;       // 9
  int* ntiles  = ctrl + 28;       // 1
  int* t_e     = ctrl + 32;
  int* t_r     = ctrl + 32 + MAXT;
  int* t_rend  = ctrl + 32 + 2 * MAXT;

  hipMemsetAsync(counts, 0, 64, stream);  // counts + cursors

  gate_kernel<<<T_TOK / 4, 256, 0, stream>>>(gate_inputs, Wg, bg, sel, wts, counts);
  scan_build_kernel<<<1, 64, 0, stream>>>(counts, offsets, ntiles, t_e, t_r, t_rend);
  scatter_kernel<<<T_TOK / 256, 256, 0, stream>>>(sel, cursors, offsets, token_list, slot_list);
  cvt_bf16_kernel<<<(T_TOK * DMODEL / 8) / 256, 256, 0, stream>>>(inputs, Xb, T_TOK * DMODEL / 8);
  transpose_cvt_kernel<<<dim3(FDIM / 64, DMODEL / 64, NEXP), 256, 0, stream>>>(w1, W1T, DMODEL, FDIM);
  transpose_cvt_kernel<<<dim3(DMODEL / 64, FDIM / 64, NEXP), 256, 0, stream>>>(w2, W2T, FDIM, DMODEL);

  hipFuncSetAttribute((const void*)gemm256_kernel<true>,
                      hipFuncAttributeMaxDynamicSharedMemorySize, 131072);
  hipFuncSetAttribute((const void*)gemm256_kernel<false>,
                      hipFuncAttributeMaxDynamicSharedMemorySize, 131072);
  // gemm1: H = gelu(X@W1+b1). grid = 8 xcd * (2 nb-sub * 80 bt)
  gemm256_kernel<true><<<8 * 2 * MAXT, 512, 131072, stream>>>(
      Xb, W1T, b1, token_list, nullptr, t_e, t_r, t_rend, ntiles, H);
  // gemm2: ys = H@W2 scatter. grid = 4 nb * 80 bt
  gemm256_kernel<false><<<4 * MAXT, 512, 131072, stream>>>(
      H, W2T, nullptr, nullptr, slot_list, t_e, t_r, t_rend, ntiles, ys);
  combine_kernel<<<(T_TOK * DMODEL / 8) / 256, 256, 0, stream>>>(ys, wts, sel, b2, out);
}

// Round 9
// 797.673 us; speedup vs baseline: 1.0507x; 1.0208x over previous
//
#include <hip/hip_runtime.h>
#include <stdint.h>

#define T_TOK 8192
#define DMODEL 1024
#define FDIM 4096
#define NEXP 8
#define NROWS 16384      // T_TOK * K
#define MAXT 80          // max 256-row tiles

typedef __bf16 bf16x8 __attribute__((ext_vector_type(8)));
typedef float f32x4 __attribute__((ext_vector_type(4)));
#define AS1 __attribute__((address_space(1)))
#define AS3 __attribute__((address_space(3)))

__device__ __forceinline__ unsigned short f2bf(float f) {
  union { float f; unsigned u; } v; v.f = f;
  unsigned r = v.u + 0x7fffu + ((v.u >> 16) & 1u);
  return (unsigned short)(r >> 16);
}
__device__ __forceinline__ float bflo(unsigned u) {
  union { unsigned u; float f; } v; v.u = u << 16; return v.f;
}
__device__ __forceinline__ float bfhi(unsigned u) {
  union { unsigned u; float f; } v; v.u = u & 0xffff0000u; return v.f;
}

// ---------------- gate: logits + top2 + softmax + expert counts ----------------
__global__ __launch_bounds__(256) void gate_kernel(
    const float* __restrict__ gx, const float* __restrict__ Wg,
    const float* __restrict__ bg, int* __restrict__ sel,
    float* __restrict__ wts, int* __restrict__ counts)
{
  int t = blockIdx.x * 4 + (threadIdx.x >> 6);
  int lane = threadIdx.x & 63;
  const float* row = gx + (size_t)t * DMODEL;
  float acc[NEXP];
#pragma unroll
  for (int e = 0; e < NEXP; ++e) acc[e] = 0.f;
  for (int d = lane; d < DMODEL; d += 64) {
    float x = row[d];
    const float* wgr = Wg + (size_t)d * NEXP;
#pragma unroll
    for (int e = 0; e < NEXP; ++e) acc[e] += x * wgr[e];
  }
#pragma unroll
  for (int off = 32; off > 0; off >>= 1) {
#pragma unroll
    for (int e = 0; e < NEXP; ++e) acc[e] += __shfl_down(acc[e], off);
  }
  if (lane == 0) {
    float lg[NEXP];
#pragma unroll
    for (int e = 0; e < NEXP; ++e) lg[e] = acc[e] + bg[e];
    int i1 = 0; float v1 = lg[0];
#pragma unroll
    for (int e = 1; e < NEXP; ++e) if (lg[e] > v1) { v1 = lg[e]; i1 = e; }
    int i2 = -1; float v2 = -3.4e38f;
#pragma unroll
    for (int e = 0; e < NEXP; ++e) if (e != i1 && lg[e] > v2) { v2 = lg[e]; i2 = e; }
    float ez = __expf(v2 - v1);           // v2 <= v1
    float s = 1.f / (1.f + ez);
    sel[t*2] = i1; sel[t*2+1] = i2;
    wts[t*2] = s;  wts[t*2+1] = ez * s;
    atomicAdd(&counts[i1], 1);
    atomicAdd(&counts[i2], 1);
  }
}

// ---------------- offsets + 256-row tile table (single thread) ----------------
__global__ void scan_build_kernel(const int* __restrict__ counts,
                                  int* __restrict__ offsets, int* __restrict__ ntiles,
                                  int* __restrict__ t_e, int* __restrict__ t_r,
                                  int* __restrict__ t_rend)
{
  if (threadIdx.x == 0 && blockIdx.x == 0) {
    int off = 0, n = 0;
    for (int e = 0; e < NEXP; ++e) {
      offsets[e] = off;
      int c = counts[e];
      for (int r = 0; r < c; r += 256) {
        t_e[n] = e; t_r[n] = off + r; t_rend[n] = off + c; ++n;
      }
      off += c;
    }
    offsets[NEXP] = off;
    *ntiles = n;
  }
}

// ---------------- scatter: compact per-expert token / slot lists --------------
__global__ __launch_bounds__(256) void scatter_kernel(
    const int* __restrict__ sel, int* __restrict__ cursors,
    const int* __restrict__ offsets, int* __restrict__ token_list,
    int* __restrict__ slot_list)
{
  int t = blockIdx.x * 256 + threadIdx.x;
  if (t >= T_TOK) return;
#pragma unroll
  for (int k = 0; k < 2; ++k) {
    int e = sel[t*2 + k];
    int pos = atomicAdd(&cursors[e], 1);
    int r = offsets[e] + pos;
    token_list[r] = t;
    slot_list[r] = t*2 + k;
  }
}

// ---------------- f32 -> bf16 (8 elems / thread) ------------------------------
__global__ __launch_bounds__(256) void cvt_bf16_kernel(
    const float* __restrict__ in, unsigned short* __restrict__ out, int n8)
{
  int i = blockIdx.x * 256 + threadIdx.x;
  if (i >= n8) return;
  const float4* in4 = (const float4*)in;
  float4 v0 = in4[(size_t)i*2], v1 = in4[(size_t)i*2 + 1];
  union { unsigned short u[8]; uint4 q; } r;
  r.u[0]=f2bf(v0.x); r.u[1]=f2bf(v0.y); r.u[2]=f2bf(v0.z); r.u[3]=f2bf(v0.w);
  r.u[4]=f2bf(v1.x); r.u[5]=f2bf(v1.y); r.u[6]=f2bf(v1.z); r.u[7]=f2bf(v1.w);
  ((uint4*)out)[i] = r.q;
}

// ---------------- [R][C] f32 -> [C][R] bf16 transpose (per expert) ------------
__global__ __launch_bounds__(256) void transpose_cvt_kernel(
    const float* __restrict__ in, unsigned short* __restrict__ out, int R, int C)
{
  __shared__ float tb[64][65];
  size_t ebase = (size_t)blockIdx.z * (size_t)R * (size_t)C;
  int r0 = blockIdx.y * 64, c0 = blockIdx.x * 64;
#pragma unroll
  for (int p = 0; p < 4; ++p) {
    int item = p * 256 + threadIdx.x;     // 1024 float4 items
    int r = item >> 4, c4 = (item & 15) * 4;
    float4 v = *(const float4*)&in[ebase + (size_t)(r0 + r) * C + (c0 + c4)];
    tb[r][c4+0] = v.x; tb[r][c4+1] = v.y; tb[r][c4+2] = v.z; tb[r][c4+3] = v.w;
  }
  __syncthreads();
#pragma unroll
  for (int p = 0; p < 2; ++p) {
    int item = p * 256 + threadIdx.x;      // 512 items: 64 c x 8 r-octs
    int c = item >> 3, r8 = (item & 7) * 8;
    union { unsigned short u[8]; uint4 q; } pk;
#pragma unroll
    for (int k = 0; k < 8; ++k) pk.u[k] = f2bf(tb[r8 + k][c]);
    *(uint4*)(out + ebase + (size_t)(c0 + c) * R + (r0 + r8)) = pk.q;
  }
}

// ---------------- grouped GEMM 256x256, BK=64, 4-phase counted-vmcnt ----------
// RACE FIX vs R8: staged halves now EQUAL the per-phase read sets.
//   A-half p  = rows {p*64..p*64+63} u {128+p*64..128+p*64+63}
//               (phase mh=p reads rows wr*128 + p*64 + i*16 + lm for wr=0,1)
//   B-half nh = rows {q*64+nh*32..q*64+nh*32+31, q=0..3}
//               (phase nh reads rows wc*64 + nh*32 + jj*16 + lm for wc=0..3)
// Stage order per tile: A0,B0,B1,A1 (consumption order). Per-wave ledger
// (2 loads/stage), steady state 8 outstanding:
//   P0: +A0' -> 10, vmcnt(6) completes A0,B0 (needs A0,B0)
//   P1: +B0' -> 8,  vmcnt(6) completes B1    (needs B1)
//   P2: +B1' -> 8,  vmcnt(6) completes A1    (needs A1)
//   P3: +A1' -> 8,  no wait (all frags register-resident)
// Tail tile waits 4/2/0. Barrier after each vmcnt extends each wave's own-load
// guarantee block-wide; sched_barrier(0) pins ds_reads below the barrier.
template<bool G1>
__global__ __launch_bounds__(512, 2) void gemm256_kernel(
    const unsigned short* __restrict__ A, const unsigned short* __restrict__ B,
    const float* __restrict__ b1, const int* __restrict__ token_list,
    const int* __restrict__ slot_list,
    const int* __restrict__ tile_e, const int* __restrict__ tile_r,
    const int* __restrict__ tile_rend, const int* __restrict__ ntiles,
    unsigned short* __restrict__ outp)
{
  constexpr int KDIM = G1 ? DMODEL : FDIM;   // K extent = A/B row stride
  constexpr int NKT  = KDIM / 64;
  constexpr int NOUT = G1 ? FDIM : DMODEL;   // output row width

  int bid = blockIdx.x;
  int nb, bt;
  if constexpr (G1) {                        // 16 nb-panels: pin 2 per XCD, bt-major
    int xcd = bid & 7, idx = bid >> 3;
    nb = xcd * 2 + (idx & 1);
    bt = idx >> 1;
  } else {                                   // 4 nb-panels, bt-major
    nb = bid & 3;
    bt = bid >> 2;
  }
  if (bt >= *ntiles) return;
  const int e = tile_e[bt], row0 = tile_r[bt], rend = tile_rend[bt];
  const int n0 = nb * 256;

  const int tid = threadIdx.x, lane = tid & 63, wave = tid >> 6;
  extern __shared__ __align__(16) char smem[];   // 131072 B

  const int lr8 = lane >> 3, g8 = lane & 7, ch = g8 ^ lr8;

  // LDS row assignments per staged half (row == tile row, LDS linear by row)
  // A-half p:  wave<4 -> p*64 + wave*16 ; wave>=4 -> 128 + p*64 + (wave-4)*16
  // B-half nh: (wave>>1)*64 + nh*32 + (wave&1)*16
  int mA[2], mB[2];
#pragma unroll
  for (int p = 0; p < 2; ++p)
    mA[p] = (wave < 4) ? (p*64 + wave*16) : (128 + p*64 + (wave-4)*16);
#pragma unroll
  for (int nh = 0; nh < 2; ++nh)
    mB[nh] = (wave >> 1)*64 + nh*32 + (wave & 1)*16;

  // global source offsets for each (half, l): row = m + l*8 + lr8
  unsigned aoffs[2][2], boffs[2][2];
#pragma unroll
  for (int p = 0; p < 2; ++p)
#pragma unroll
    for (int l = 0; l < 2; ++l) {
      int m = mA[p] + l*8 + lr8;
      int row = row0 + m; if (row > NROWS - 1) row = NROWS - 1;
      int arow = G1 ? token_list[row] : row;
      aoffs[p][l] = (unsigned)arow * KDIM + ch*8;
      int mb = mB[p] + l*8 + lr8;
      boffs[p][l] = (unsigned)(e * NOUT + n0 + mb) * KDIM + ch*8;
    }

  // stage one 16KB half (p: 0/1 = A-half, 2/3 = B-half); 2 loads per wave
  auto stage_half = [&](int p, int ktn, int bsel) {
    const int kb = ktn * 64;
    char* base = smem + bsel * 65536;
    if (p < 2) {
#pragma unroll
      for (int l = 0; l < 2; ++l)
        __builtin_amdgcn_global_load_lds(
            (const AS1 void*)(A + aoffs[p][l] + kb),
            (AS3 void*)(base + ((mA[p] + l*8) << 7)), 16, 0, 0);
    } else {
      const int nh = p - 2;
#pragma unroll
      for (int l = 0; l < 2; ++l)
        __builtin_amdgcn_global_load_lds(
            (const AS1 void*)(B + boffs[nh][l] + kb),
            (AS3 void*)(base + 32768 + ((mB[nh] + l*8) << 7)), 16, 0, 0);
    }
  };

  f32x4 acc[8][4] = {};
  bf16x8 aR[4][2];        // current A-half: 4 row-frags x 2 k-slices
  bf16x8 bR[2][2][2];     // both B-halves: [nh][jj][ks]
  const int wr = wave >> 2, wc = wave & 3;
  const int lm = lane & 15, lk = lane >> 4, l7 = lane & 7;
  const unsigned abase = (unsigned)(wr*128 + lm) * 128;
  const unsigned bbase = 32768u + (unsigned)(wc*64 + lm) * 128;
  const unsigned kx0 = (unsigned)((lk ^ l7) << 4);
  const unsigned kx1 = (unsigned)(((4 + lk) ^ l7) << 4);

  auto rdA = [&](const char* base, int mh) {
#pragma unroll
    for (int i = 0; i < 4; ++i) {
      const char* pA = base + abase + mh*8192 + i*2048;   // row wr*128+mh*64+i*16+lm
      aR[i][0] = *(const bf16x8*)(pA + kx0);
      aR[i][1] = *(const bf16x8*)(pA + kx1);
    }
  };
  auto rdB = [&](const char* base, int nh) {
#pragma unroll
    for (int jj = 0; jj < 2; ++jj) {
      const char* pB = base + bbase + nh*4096 + jj*2048;  // row wc*64+nh*32+jj*16+lm
      bR[nh][jj][0] = *(const bf16x8*)(pB + kx0);
      bR[nh][jj][1] = *(const bf16x8*)(pB + kx1);
    }
  };
  auto mm = [&](int mh, int nh) {
    __builtin_amdgcn_s_setprio(1);
#pragma unroll
    for (int i = 0; i < 4; ++i)
#pragma unroll
      for (int jj = 0; jj < 2; ++jj) {
        acc[mh*4+i][nh*2+jj] = __builtin_amdgcn_mfma_f32_16x16x32_bf16(
            aR[i][0], bR[nh][jj][0], acc[mh*4+i][nh*2+jj], 0, 0, 0);
        acc[mh*4+i][nh*2+jj] = __builtin_amdgcn_mfma_f32_16x16x32_bf16(
            aR[i][1], bR[nh][jj][1], acc[mh*4+i][nh*2+jj], 0, 0, 0);
      }
    __builtin_amdgcn_s_setprio(0);
  };

  // prologue: stage tile 0 halves in consumption order A0,B0,B1,A1
  stage_half(0, 0, 0);
  stage_half(2, 0, 0);
  stage_half(3, 0, 0);
  stage_half(1, 0, 0);

  for (int kt = 0; kt < NKT; ++kt) {
    const int b = kt & 1;
    const int nxt = b ^ 1;
    const char* base = smem + b * 65536;
    const bool pre = (kt + 1 < NKT);
    // ---- P0: quad (0,0); needs A0,B0 ----
    if (pre) {
      stage_half(0, kt + 1, nxt);
      asm volatile("s_waitcnt vmcnt(6)" ::: "memory");
    } else {
      asm volatile("s_waitcnt vmcnt(4)" ::: "memory");
    }
    __builtin_amdgcn_s_barrier();
    __builtin_amdgcn_sched_barrier(0);
    rdA(base, 0); rdB(base, 0);
    asm volatile("s_waitcnt lgkmcnt(0)" ::: "memory");
    __builtin_amdgcn_sched_barrier(0);
    mm(0, 0);
    __builtin_amdgcn_s_barrier();
    // ---- P1: quad (0,1); needs B1 ----
    if (pre) {
      stage_half(2, kt + 1, nxt);
      asm volatile("s_waitcnt vmcnt(6)" ::: "memory");
    } else {
      asm volatile("s_waitcnt vmcnt(2)" ::: "memory");
    }
    __builtin_amdgcn_s_barrier();
    __builtin_amdgcn_sched_barrier(0);
    rdB(base, 1);
    asm volatile("s_waitcnt lgkmcnt(0)" ::: "memory");
    __builtin_amdgcn_sched_barrier(0);
    mm(0, 1);
    __builtin_amdgcn_s_barrier();
    // ---- P2: quad (1,1); needs A1 ----
    if (pre) {
      stage_half(3, kt + 1, nxt);
      asm volatile("s_waitcnt vmcnt(6)" ::: "memory");
    } else {
      asm volatile("s_waitcnt vmcnt(0)" ::: "memory");
    }
    __builtin_amdgcn_s_barrier();
    __builtin_amdgcn_sched_barrier(0);
    rdA(base, 1);
    asm volatile("s_waitcnt lgkmcnt(0)" ::: "memory");
    __builtin_amdgcn_sched_barrier(0);
    mm(1, 1);
    __builtin_amdgcn_s_barrier();
    // ---- P3: quad (1,0); no reads (aR=A1, bR0 resident) ----
    if (pre) stage_half(1, kt + 1, nxt);
    mm(1, 0);
    __builtin_amdgcn_s_barrier();
    __builtin_amdgcn_sched_barrier(0);
  }

  asm volatile("" ::: "memory");
  float bias[4] = {};
  if constexpr (G1) {
#pragma unroll
    for (int j = 0; j < 4; ++j) bias[j] = b1[(size_t)e * FDIM + n0 + wc*64 + j*16 + lm];
  }

  // epilogue: 8 chunks of 32 rows; [gelu] -> f32 LDS (stride 260) -> bf16 x8
  float* eps = (float*)smem;
#pragma unroll
  for (int c = 0; c < 8; ++c) {
    __syncthreads();
    if (wr == (c >> 2)) {
#pragma unroll
      for (int ii = 0; ii < 2; ++ii) {
        const int mi = (c & 3) * 2 + ii;
#pragma unroll
        for (int j = 0; j < 4; ++j) {
#pragma unroll
          for (int r = 0; r < 4; ++r) {
            float v = acc[mi][j][r];
            if constexpr (G1) {
              v += bias[j];
              float z2 = 1.5957691216f * (v + 0.044715f * v * v * v);
              v = v / (1.f + __expf(-z2));
            }
            eps[(ii*16 + lk*4 + r) * 260 + wc*64 + j*16 + lm] = v;
          }
        }
      }
    }
    __syncthreads();
#pragma unroll
    for (int u = 0; u < 2; ++u) {
      int item = u * 512 + tid;               // 1024 items: 32 rows x 32 octs
      int lrow = item >> 5, c8 = (item & 31) * 8;
      int gr = row0 + c * 32 + lrow;
      if (gr < rend) {
        float4 v0 = *(const float4*)&eps[lrow * 260 + c8];
        float4 v1 = *(const float4*)&eps[lrow * 260 + c8 + 4];
        union { unsigned short u[8]; uint4 q; } pk;
        pk.u[0]=f2bf(v0.x); pk.u[1]=f2bf(v0.y); pk.u[2]=f2bf(v0.z); pk.u[3]=f2bf(v0.w);
        pk.u[4]=f2bf(v1.x); pk.u[5]=f2bf(v1.y); pk.u[6]=f2bf(v1.z); pk.u[7]=f2bf(v1.w);
        size_t orow;
        if constexpr (G1) orow = (size_t)gr * FDIM;
        else              orow = (size_t)slot_list[gr] * DMODEL;
        *(uint4*)(outp + orow + n0 + c8) = pk.q;
      }
    }
  }
}

// ---------------- combine: out = sum_k w_k*(y_k + b2[e_k]) --------------------
__global__ __launch_bounds__(256) void combine_kernel(
    const unsigned short* __restrict__ ys, const float* __restrict__ wts,
    const int* __restrict__ sel, const float* __restrict__ b2,
    float* __restrict__ out)
{
  int i = blockIdx.x * 256 + threadIdx.x;   // over T*D/8
  int t = i >> 7, d8 = i & 127;
  float w0 = wts[t*2], w1 = wts[t*2 + 1];
  int e0 = sel[t*2], e1 = sel[t*2 + 1];
  const uint4* ys4 = (const uint4*)ys;
  uint4 ya = ys4[(size_t)(t*2) * 128 + d8];
  uint4 yb = ys4[(size_t)(t*2 + 1) * 128 + d8];
  const float4* b24 = (const float4*)b2;
  float4 c0a = b24[e0*256 + d8*2], c0b = b24[e0*256 + d8*2 + 1];
  float4 c1a = b24[e1*256 + d8*2], c1b = b24[e1*256 + d8*2 + 1];
  float4 o0, o1;
  o0.x = w0*(bflo(ya.x)+c0a.x) + w1*(bflo(yb.x)+c1a.x);
  o0.y = w0*(bfhi(ya.x)+c0a.y) + w1*(bfhi(yb.x)+c1a.y);
  o0.z = w0*(bflo(ya.y)+c0a.z) + w1*(bflo(yb.y)+c1a.z);
  o0.w = w0*(bfhi(ya.y)+c0a.w) + w1*(bfhi(yb.y)+c1a.w);
  o1.x = w0*(bflo(ya.z)+c0b.x) + w1*(bflo(yb.z)+c1b.x);
  o1.y = w0*(bfhi(ya.z)+c0b.y) + w1*(bfhi(yb.z)+c1b.y);
  o1.z = w0*(bflo(ya.w)+c0b.z) + w1*(bflo(yb.w)+c1b.z);
  o1.w = w0*(bfhi(ya.w)+c0b.w) + w1*(bfhi(yb.w)+c1b.w);
  float4* out4 = (float4*)out;
  out4[(size_t)t * 256 + d8*2]     = o0;
  out4[(size_t)t * 256 + d8*2 + 1] = o1;
}

// ---------------- host ---------------------------------------------------------
extern "C" void kernel_launch(void* const* d_in, const int* in_sizes, int n_in,
                              void* d_out, int out_size, void* d_ws, size_t ws_size,
                              hipStream_t stream)
{
  const float* gate_inputs = (const float*)d_in[0];
  const float* inputs      = (const float*)d_in[1];
  const float* Wg          = (const float*)d_in[2];
  const float* bg          = (const float*)d_in[3];
  const float* w1          = (const float*)d_in[4];
  const float* b1          = (const float*)d_in[5];
  const float* w2          = (const float*)d_in[6];
  const float* b2          = (const float*)d_in[7];
  float* out = (float*)d_out;

  char* ws = (char*)d_ws;
  size_t o = 0;
  auto carve = [&](size_t bytes) { void* p = ws + o; o += (bytes + 255) & ~(size_t)255; return p; };
  unsigned short* Xb  = (unsigned short*)carve((size_t)T_TOK * DMODEL * 2);
  unsigned short* W1T = (unsigned short*)carve((size_t)NEXP * FDIM * DMODEL * 2);
  unsigned short* W2T = (unsigned short*)carve((size_t)NEXP * DMODEL * FDIM * 2);
  unsigned short* H   = (unsigned short*)carve((size_t)NROWS * FDIM * 2);
  unsigned short* ys  = (unsigned short*)carve((size_t)NROWS * DMODEL * 2);
  int*   sel          = (int*)carve((size_t)NROWS * 4);
  float* wts          = (float*)carve((size_t)NROWS * 4);
  int*   token_list   = (int*)carve((size_t)(NROWS + 256) * 4);
  int*   slot_list    = (int*)carve((size_t)(NROWS + 256) * 4);
  int*   ctrl         = (int*)carve(4096);
  int* counts  = ctrl;            // 8
  int* cursors = ctrl + 8;        // 8
  int* offsets = ctrl + 16;       // 9
  int* ntiles  = ctrl + 28;       // 1
  int* t_e     = ctrl + 32;
  int* t_r     = ctrl + 32 + MAXT;
  int* t_rend  = ctrl + 32 + 2 * MAXT;

  hipMemsetAsync(counts, 0, 64, stream);  // counts + cursors

  gate_kernel<<<T_TOK / 4, 256, 0, stream>>>(gate_inputs, Wg, bg, sel, wts, counts);
  scan_build_kernel<<<1, 64, 0, stream>>>(counts, offsets, ntiles, t_e, t_r, t_rend);
  scatter_kernel<<<T_TOK / 256, 256, 0, stream>>>(sel, cursors, offsets, token_list, slot_list);
  cvt_bf16_kernel<<<(T_TOK * DMODEL / 8) / 256, 256, 0, stream>>>(inputs, Xb, T_TOK * DMODEL / 8);
  transpose_cvt_kernel<<<dim3(FDIM / 64, DMODEL / 64, NEXP), 256, 0, stream>>>(w1, W1T, DMODEL, FDIM);
  transpose_cvt_kernel<<<dim3(DMODEL / 64, FDIM / 64, NEXP), 256, 0, stream>>>(w2, W2T, FDIM, DMODEL);

  hipFuncSetAttribute((const void*)gemm256_kernel<true>,
                      hipFuncAttributeMaxDynamicSharedMemorySize, 131072);
  hipFuncSetAttribute((const void*)gemm256_kernel<false>,
                      hipFuncAttributeMaxDynamicSharedMemorySize, 131072);
  // gemm1: H = gelu(X@W1+b1). grid = 8 xcd * (2 nb-sub * 80 bt)
  gemm256_kernel<true><<<8 * 2 * MAXT, 512, 131072, stream>>>(
      Xb, W1T, b1, token_list, nullptr, t_e, t_r, t_rend, ntiles, H);
  // gemm2: ys = H@W2 scatter. grid = 4 nb * 80 bt
  gemm256_kernel<false><<<4 * MAXT, 512, 131072, stream>>>(
      H, W2T, nullptr, nullptr, slot_list, t_e, t_r, t_rend, ntiles, ys);
  combine_kernel<<<(T_TOK * DMODEL / 8) / 256, 256, 0, stream>>>(ys, wts, sel, b2, out);
}

// Round 10
// 706.015 us; speedup vs baseline: 1.1871x; 1.1298x over previous
//
#include <hip/hip_runtime.h>
#include <stdint.h>

#define T_TOK 8192
#define DMODEL 1024
#define FDIM 4096
#define NEXP 8
#define NROWS 16384      // T_TOK * K
#define MAXT 80          // max 256-row tiles

// prep_kernel block ranges
#define GATE_BLKS 2048                  // T_TOK/4
#define CVT_BLKS  4096                  // T*D/8/256
#define TR1_BLKS  8192                  // 64 x 16 x 8
#define TR2_BLKS  8192                  // 16 x 64 x 8
#define PREP_BLKS (GATE_BLKS + CVT_BLKS + TR1_BLKS + TR2_BLKS)

typedef __bf16 bf16x8 __attribute__((ext_vector_type(8)));
typedef float f32x4 __attribute__((ext_vector_type(4)));
#define AS1 __attribute__((address_space(1)))
#define AS3 __attribute__((address_space(3)))

__device__ __forceinline__ unsigned short f2bf(float f) {
  union { float f; unsigned u; } v; v.f = f;
  unsigned r = v.u + 0x7fffu + ((v.u >> 16) & 1u);
  return (unsigned short)(r >> 16);
}
__device__ __forceinline__ float bflo(unsigned u) {
  union { unsigned u; float f; } v; v.u = u << 16; return v.f;
}
__device__ __forceinline__ float bfhi(unsigned u) {
  union { unsigned u; float f; } v; v.u = u & 0xffff0000u; return v.f;
}

// ---------------- fused prep: gate || f32->bf16 cvt || both W transposes ------
__device__ __forceinline__ void transpose_body(
    const float* __restrict__ in, unsigned short* __restrict__ out,
    int R, int C, int bx, int by, int bz, float (*tb)[65])
{
  size_t ebase = (size_t)bz * (size_t)R * (size_t)C;
  int r0 = by * 64, c0 = bx * 64;
#pragma unroll
  for (int p = 0; p < 4; ++p) {
    int item = p * 256 + threadIdx.x;     // 1024 float4 items
    int r = item >> 4, c4 = (item & 15) * 4;
    float4 v = *(const float4*)&in[ebase + (size_t)(r0 + r) * C + (c0 + c4)];
    tb[r][c4+0] = v.x; tb[r][c4+1] = v.y; tb[r][c4+2] = v.z; tb[r][c4+3] = v.w;
  }
  __syncthreads();
#pragma unroll
  for (int p = 0; p < 2; ++p) {
    int item = p * 256 + threadIdx.x;      // 512 items: 64 c x 8 r-octs
    int c = item >> 3, r8 = (item & 7) * 8;
    union { unsigned short u[8]; uint4 q; } pk;
#pragma unroll
    for (int k = 0; k < 8; ++k) pk.u[k] = f2bf(tb[r8 + k][c]);
    *(uint4*)(out + ebase + (size_t)(c0 + c) * R + (r0 + r8)) = pk.q;
  }
}

__global__ __launch_bounds__(256) void prep_kernel(
    const float* __restrict__ gx, const float* __restrict__ Wg,
    const float* __restrict__ bg, int* __restrict__ sel,
    float* __restrict__ wts, int* __restrict__ counts,
    const float* __restrict__ inputs, unsigned short* __restrict__ Xb,
    const float* __restrict__ w1, unsigned short* __restrict__ W1T,
    const float* __restrict__ w2, unsigned short* __restrict__ W2T)
{
  __shared__ float tb[64][65];
  int b = blockIdx.x;
  if (b < GATE_BLKS) {
    // ---- gate: logits + top2 + softmax + expert counts ----
    int t = b * 4 + (threadIdx.x >> 6);
    int lane = threadIdx.x & 63;
    const float* row = gx + (size_t)t * DMODEL;
    float acc[NEXP];
#pragma unroll
    for (int e = 0; e < NEXP; ++e) acc[e] = 0.f;
    for (int d = lane; d < DMODEL; d += 64) {
      float x = row[d];
      const float* wgr = Wg + (size_t)d * NEXP;
#pragma unroll
      for (int e = 0; e < NEXP; ++e) acc[e] += x * wgr[e];
    }
#pragma unroll
    for (int off = 32; off > 0; off >>= 1) {
#pragma unroll
      for (int e = 0; e < NEXP; ++e) acc[e] += __shfl_down(acc[e], off);
    }
    if (lane == 0) {
      float lg[NEXP];
#pragma unroll
      for (int e = 0; e < NEXP; ++e) lg[e] = acc[e] + bg[e];
      int i1 = 0; float v1 = lg[0];
#pragma unroll
      for (int e = 1; e < NEXP; ++e) if (lg[e] > v1) { v1 = lg[e]; i1 = e; }
      int i2 = -1; float v2 = -3.4e38f;
#pragma unroll
      for (int e = 0; e < NEXP; ++e) if (e != i1 && lg[e] > v2) { v2 = lg[e]; i2 = e; }
      float ez = __expf(v2 - v1);           // v2 <= v1
      float s = 1.f / (1.f + ez);
      sel[t*2] = i1; sel[t*2+1] = i2;
      wts[t*2] = s;  wts[t*2+1] = ez * s;
      atomicAdd(&counts[i1], 1);
      atomicAdd(&counts[i2], 1);
    }
  } else if (b < GATE_BLKS + CVT_BLKS) {
    // ---- f32 -> bf16 (8 elems / thread) ----
    int i = (b - GATE_BLKS) * 256 + threadIdx.x;
    const float4* in4 = (const float4*)inputs;
    float4 v0 = in4[(size_t)i*2], v1 = in4[(size_t)i*2 + 1];
    union { unsigned short u[8]; uint4 q; } r;
    r.u[0]=f2bf(v0.x); r.u[1]=f2bf(v0.y); r.u[2]=f2bf(v0.z); r.u[3]=f2bf(v0.w);
    r.u[4]=f2bf(v1.x); r.u[5]=f2bf(v1.y); r.u[6]=f2bf(v1.z); r.u[7]=f2bf(v1.w);
    ((uint4*)Xb)[i] = r.q;
  } else if (b < GATE_BLKS + CVT_BLKS + TR1_BLKS) {
    // ---- w1 [E][1024][4096] -> W1T [E][4096][1024] ----
    int bp = b - (GATE_BLKS + CVT_BLKS);
    transpose_body(w1, W1T, DMODEL, FDIM, bp & 63, (bp >> 6) & 15, bp >> 10, tb);
  } else {
    // ---- w2 [E][4096][1024] -> W2T [E][1024][4096] ----
    int bp = b - (GATE_BLKS + CVT_BLKS + TR1_BLKS);
    transpose_body(w2, W2T, FDIM, DMODEL, bp & 15, (bp >> 4) & 63, bp >> 10, tb);
  }
}

// ---------------- offsets + 256-row tile table (parallel, 1 block) ------------
__global__ __launch_bounds__(256) void scan_build_kernel(
    const int* __restrict__ counts, int* __restrict__ offsets,
    int* __restrict__ ntiles, int* __restrict__ t_e, int* __restrict__ t_r,
    int* __restrict__ t_rend)
{
  __shared__ int sc[8], soff[9], stile[9];
  int tid = threadIdx.x;
  if (tid < 8) sc[tid] = counts[tid];
  __syncthreads();
  if (tid == 0) {
    int off = 0, tl = 0;
#pragma unroll
    for (int e = 0; e < NEXP; ++e) {
      soff[e] = off; stile[e] = tl;
      off += sc[e];
      tl += (sc[e] + 255) >> 8;
    }
    soff[8] = off; stile[8] = tl;
  }
  __syncthreads();
  int ntot = stile[8];
  for (int idx = tid; idx < ntot; idx += 256) {
    int e = 0;
#pragma unroll
    for (int q = 0; q < NEXP; ++q) if (idx >= stile[q + 1]) e = q + 1;
    int r = (idx - stile[e]) * 256;
    t_e[idx] = e; t_r[idx] = soff[e] + r; t_rend[idx] = soff[e] + sc[e];
  }
  if (tid < 9) offsets[tid] = soff[tid];
  if (tid == 0) *ntiles = ntot;
}

// ---------------- scatter: wave-aggregated per-expert atomics -----------------
__global__ __launch_bounds__(256) void scatter_kernel(
    const int* __restrict__ sel, int* __restrict__ cursors,
    const int* __restrict__ offsets, int* __restrict__ token_list,
    int* __restrict__ slot_list)
{
  int t = blockIdx.x * 256 + threadIdx.x;
  int lane = threadIdx.x & 63;
  unsigned long long ltmask = (lane == 63) ? 0x7fffffffffffffffull
                                           : ((1ull << lane) - 1ull);
#pragma unroll
  for (int k = 0; k < 2; ++k) {
    int e = sel[t*2 + k];
#pragma unroll
    for (int ex = 0; ex < NEXP; ++ex) {
      unsigned long long m = __ballot(e == ex);
      if (m == 0ull) continue;                  // wave-uniform
      if (e == ex) {
        int leader = __ffsll((unsigned long long)m) - 1;
        int cnt = __popcll(m);
        int base = 0;
        if (lane == leader) base = atomicAdd(&cursors[ex], cnt);
        base = __shfl(base, leader);
        int r = offsets[ex] + base + __popcll(m & ltmask);
        token_list[r] = t;
        slot_list[r] = t*2 + k;
      }
    }
  }
}

// ---------------- grouped GEMM 256x256, BK=64, 4-phase counted-vmcnt ----------
// (unchanged from R9 — verified passing)
//   A-half p  = rows {p*64..p*64+63} u {128+p*64..128+p*64+63}
//   B-half nh = rows {q*64+nh*32..q*64+nh*32+31, q=0..3}
// Stage order A0,B0,B1,A1; steady-state vmcnt(6); tail 4/2/0.
template<bool G1>
__global__ __launch_bounds__(512, 2) void gemm256_kernel(
    const unsigned short* __restrict__ A, const unsigned short* __restrict__ B,
    const float* __restrict__ b1, const int* __restrict__ token_list,
    const int* __restrict__ slot_list,
    const int* __restrict__ tile_e, const int* __restrict__ tile_r,
    const int* __restrict__ tile_rend, const int* __restrict__ ntiles,
    unsigned short* __restrict__ outp)
{
  constexpr int KDIM = G1 ? DMODEL : FDIM;   // K extent = A/B row stride
  constexpr int NKT  = KDIM / 64;
  constexpr int NOUT = G1 ? FDIM : DMODEL;   // output row width

  int bid = blockIdx.x;
  int nb, bt;
  if constexpr (G1) {                        // 16 nb-panels: pin 2 per XCD, bt-major
    int xcd = bid & 7, idx = bid >> 3;
    nb = xcd * 2 + (idx & 1);
    bt = idx >> 1;
  } else {                                   // 4 nb-panels, bt-major
    nb = bid & 3;
    bt = bid >> 2;
  }
  if (bt >= *ntiles) return;
  const int e = tile_e[bt], row0 = tile_r[bt], rend = tile_rend[bt];
  const int n0 = nb * 256;

  const int tid = threadIdx.x, lane = tid & 63, wave = tid >> 6;
  extern __shared__ __align__(16) char smem[];   // 131072 B

  const int lr8 = lane >> 3, g8 = lane & 7, ch = g8 ^ lr8;

  int mA[2], mB[2];
#pragma unroll
  for (int p = 0; p < 2; ++p)
    mA[p] = (wave < 4) ? (p*64 + wave*16) : (128 + p*64 + (wave-4)*16);
#pragma unroll
  for (int nh = 0; nh < 2; ++nh)
    mB[nh] = (wave >> 1)*64 + nh*32 + (wave & 1)*16;

  unsigned aoffs[2][2], boffs[2][2];
#pragma unroll
  for (int p = 0; p < 2; ++p)
#pragma unroll
    for (int l = 0; l < 2; ++l) {
      int m = mA[p] + l*8 + lr8;
      int row = row0 + m; if (row > NROWS - 1) row = NROWS - 1;
      int arow = G1 ? token_list[row] : row;
      aoffs[p][l] = (unsigned)arow * KDIM + ch*8;
      int mb = mB[p] + l*8 + lr8;
      boffs[p][l] = (unsigned)(e * NOUT + n0 + mb) * KDIM + ch*8;
    }

  auto stage_half = [&](int p, int ktn, int bsel) {
    const int kb = ktn * 64;
    char* base = smem + bsel * 65536;
    if (p < 2) {
#pragma unroll
      for (int l = 0; l < 2; ++l)
        __builtin_amdgcn_global_load_lds(
            (const AS1 void*)(A + aoffs[p][l] + kb),
            (AS3 void*)(base + ((mA[p] + l*8) << 7)), 16, 0, 0);
    } else {
      const int nh = p - 2;
#pragma unroll
      for (int l = 0; l < 2; ++l)
        __builtin_amdgcn_global_load_lds(
            (const AS1 void*)(B + boffs[nh][l] + kb),
            (AS3 void*)(base + 32768 + ((mB[nh] + l*8) << 7)), 16, 0, 0);
    }
  };

  f32x4 acc[8][4] = {};
  bf16x8 aR[4][2];        // current A-half: 4 row-frags x 2 k-slices
  bf16x8 bR[2][2][2];     // both B-halves: [nh][jj][ks]
  const int wr = wave >> 2, wc = wave & 3;
  const int lm = lane & 15, lk = lane >> 4, l7 = lane & 7;
  const unsigned abase = (unsigned)(wr*128 + lm) * 128;
  const unsigned bbase = 32768u + (unsigned)(wc*64 + lm) * 128;
  const unsigned kx0 = (unsigned)((lk ^ l7) << 4);
  const unsigned kx1 = (unsigned)(((4 + lk) ^ l7) << 4);

  auto rdA = [&](const char* base, int mh) {
#pragma unroll
    for (int i = 0; i < 4; ++i) {
      const char* pA = base + abase + mh*8192 + i*2048;   // row wr*128+mh*64+i*16+lm
      aR[i][0] = *(const bf16x8*)(pA + kx0);
      aR[i][1] = *(const bf16x8*)(pA + kx1);
    }
  };
  auto rdB = [&](const char* base, int nh) {
#pragma unroll
    for (int jj = 0; jj < 2; ++jj) {
      const char* pB = base + bbase + nh*4096 + jj*2048;  // row wc*64+nh*32+jj*16+lm
      bR[nh][jj][0] = *(const bf16x8*)(pB + kx0);
      bR[nh][jj][1] = *(const bf16x8*)(pB + kx1);
    }
  };
  auto mm = [&](int mh, int nh) {
    __builtin_amdgcn_s_setprio(1);
#pragma unroll
    for (int i = 0; i < 4; ++i)
#pragma unroll
      for (int jj = 0; jj < 2; ++jj) {
        acc[mh*4+i][nh*2+jj] = __builtin_amdgcn_mfma_f32_16x16x32_bf16(
            aR[i][0], bR[nh][jj][0], acc[mh*4+i][nh*2+jj], 0, 0, 0);
        acc[mh*4+i][nh*2+jj] = __builtin_amdgcn_mfma_f32_16x16x32_bf16(
            aR[i][1], bR[nh][jj][1], acc[mh*4+i][nh*2+jj], 0, 0, 0);
      }
    __builtin_amdgcn_s_setprio(0);
  };

  // prologue: stage tile 0 halves in consumption order A0,B0,B1,A1
  stage_half(0, 0, 0);
  stage_half(2, 0, 0);
  stage_half(3, 0, 0);
  stage_half(1, 0, 0);

  for (int kt = 0; kt < NKT; ++kt) {
    const int b = kt & 1;
    const int nxt = b ^ 1;
    const char* base = smem + b * 65536;
    const bool pre = (kt + 1 < NKT);
    // ---- P0: quad (0,0); needs A0,B0 ----
    if (pre) {
      stage_half(0, kt + 1, nxt);
      asm volatile("s_waitcnt vmcnt(6)" ::: "memory");
    } else {
      asm volatile("s_waitcnt vmcnt(4)" ::: "memory");
    }
    __builtin_amdgcn_s_barrier();
    __builtin_amdgcn_sched_barrier(0);
    rdA(base, 0); rdB(base, 0);
    asm volatile("s_waitcnt lgkmcnt(0)" ::: "memory");
    __builtin_amdgcn_sched_barrier(0);
    mm(0, 0);
    __builtin_amdgcn_s_barrier();
    // ---- P1: quad (0,1); needs B1 ----
    if (pre) {
      stage_half(2, kt + 1, nxt);
      asm volatile("s_waitcnt vmcnt(6)" ::: "memory");
    } else {
      asm volatile("s_waitcnt vmcnt(2)" ::: "memory");
    }
    __builtin_amdgcn_s_barrier();
    __builtin_amdgcn_sched_barrier(0);
    rdB(base, 1);
    asm volatile("s_waitcnt lgkmcnt(0)" ::: "memory");
    __builtin_amdgcn_sched_barrier(0);
    mm(0, 1);
    __builtin_amdgcn_s_barrier();
    // ---- P2: quad (1,1); needs A1 ----
    if (pre) {
      stage_half(3, kt + 1, nxt);
      asm volatile("s_waitcnt vmcnt(6)" ::: "memory");
    } else {
      asm volatile("s_waitcnt vmcnt(0)" ::: "memory");
    }
    __builtin_amdgcn_s_barrier();
    __builtin_amdgcn_sched_barrier(0);
    rdA(base, 1);
    asm volatile("s_waitcnt lgkmcnt(0)" ::: "memory");
    __builtin_amdgcn_sched_barrier(0);
    mm(1, 1);
    __builtin_amdgcn_s_barrier();
    // ---- P3: quad (1,0); no reads (aR=A1, bR0 resident) ----
    if (pre) stage_half(1, kt + 1, nxt);
    mm(1, 0);
    __builtin_amdgcn_s_barrier();
    __builtin_amdgcn_sched_barrier(0);
  }

  asm volatile("" ::: "memory");
  float bias[4] = {};
  if constexpr (G1) {
#pragma unroll
    for (int j = 0; j < 4; ++j) bias[j] = b1[(size_t)e * FDIM + n0 + wc*64 + j*16 + lm];
  }

  // epilogue: 8 chunks of 32 rows; [gelu] -> f32 LDS (stride 260) -> bf16 x8
  float* eps = (float*)smem;
#pragma unroll
  for (int c = 0; c < 8; ++c) {
    __syncthreads();
    if (wr == (c >> 2)) {
#pragma unroll
      for (int ii = 0; ii < 2; ++ii) {
        const int mi = (c & 3) * 2 + ii;
#pragma unroll
        for (int j = 0; j < 4; ++j) {
#pragma unroll
          for (int r = 0; r < 4; ++r) {
            float v = acc[mi][j][r];
            if constexpr (G1) {
              v += bias[j];
              float z2 = 1.5957691216f * (v + 0.044715f * v * v * v);
              v = v / (1.f + __expf(-z2));
            }
            eps[(ii*16 + lk*4 + r) * 260 + wc*64 + j*16 + lm] = v;
          }
        }
      }
    }
    __syncthreads();
#pragma unroll
    for (int u = 0; u < 2; ++u) {
      int item = u * 512 + tid;               // 1024 items: 32 rows x 32 octs
      int lrow = item >> 5, c8 = (item & 31) * 8;
      int gr = row0 + c * 32 + lrow;
      if (gr < rend) {
        float4 v0 = *(const float4*)&eps[lrow * 260 + c8];
        float4 v1 = *(const float4*)&eps[lrow * 260 + c8 + 4];
        union { unsigned short u[8]; uint4 q; } pk;
        pk.u[0]=f2bf(v0.x); pk.u[1]=f2bf(v0.y); pk.u[2]=f2bf(v0.z); pk.u[3]=f2bf(v0.w);
        pk.u[4]=f2bf(v1.x); pk.u[5]=f2bf(v1.y); pk.u[6]=f2bf(v1.z); pk.u[7]=f2bf(v1.w);
        size_t orow;
        if constexpr (G1) orow = (size_t)gr * FDIM;
        else              orow = (size_t)slot_list[gr] * DMODEL;
        *(uint4*)(outp + orow + n0 + c8) = pk.q;
      }
    }
  }
}

// ---------------- combine: out = sum_k w_k*(y_k + b2[e_k]) --------------------
__global__ __launch_bounds__(256) void combine_kernel(
    const unsigned short* __restrict__ ys, const float* __restrict__ wts,
    const int* __restrict__ sel, const float* __restrict__ b2,
    float* __restrict__ out)
{
  int i = blockIdx.x * 256 + threadIdx.x;   // over T*D/8
  int t = i >> 7, d8 = i & 127;
  float w0 = wts[t*2], w1 = wts[t*2 + 1];
  int e0 = sel[t*2], e1 = sel[t*2 + 1];
  const uint4* ys4 = (const uint4*)ys;
  uint4 ya = ys4[(size_t)(t*2) * 128 + d8];
  uint4 yb = ys4[(size_t)(t*2 + 1) * 128 + d8];
  const float4* b24 = (const float4*)b2;
  float4 c0a = b24[e0*256 + d8*2], c0b = b24[e0*256 + d8*2 + 1];
  float4 c1a = b24[e1*256 + d8*2], c1b = b24[e1*256 + d8*2 + 1];
  float4 o0, o1;
  o0.x = w0*(bflo(ya.x)+c0a.x) + w1*(bflo(yb.x)+c1a.x);
  o0.y = w0*(bfhi(ya.x)+c0a.y) + w1*(bfhi(yb.x)+c1a.y);
  o0.z = w0*(bflo(ya.y)+c0a.z) + w1*(bflo(yb.y)+c1a.z);
  o0.w = w0*(bfhi(ya.y)+c0a.w) + w1*(bfhi(yb.y)+c1a.w);
  o1.x = w0*(bflo(ya.z)+c0b.x) + w1*(bflo(yb.z)+c1b.x);
  o1.y = w0*(bfhi(ya.z)+c0b.y) + w1*(bfhi(yb.z)+c1b.y);
  o1.z = w0*(bflo(ya.w)+c0b.z) + w1*(bflo(yb.w)+c1b.z);
  o1.w = w0*(bfhi(ya.w)+c0b.w) + w1*(bfhi(yb.w)+c1b.w);
  float4* out4 = (float4*)out;
  out4[(size_t)t * 256 + d8*2]     = o0;
  out4[(size_t)t * 256 + d8*2 + 1] = o1;
}

// ---------------- host ---------------------------------------------------------
extern "C" void kernel_launch(void* const* d_in, const int* in_sizes, int n_in,
                              void* d_out, int out_size, void* d_ws, size_t ws_size,
                              hipStream_t stream)
{
  const float* gate_inputs = (const float*)d_in[0];
  const float* inputs      = (const float*)d_in[1];
  const float* Wg          = (const float*)d_in[2];
  const float* bg          = (const float*)d_in[3];
  const float* w1          = (const float*)d_in[4];
  const float* b1          = (const float*)d_in[5];
  const float* w2          = (const float*)d_in[6];
  const float* b2          = (const float*)d_in[7];
  float* out = (float*)d_out;

  char* ws = (char*)d_ws;
  size_t o = 0;
  auto carve = [&](size_t bytes) { void* p = ws + o; o += (bytes + 255) & ~(size_t)255; return p; };
  unsigned short* Xb  = (unsigned short*)carve((size_t)T_TOK * DMODEL * 2);
  unsigned short* W1T = (unsigned short*)carve((size_t)NEXP * FDIM * DMODEL * 2);
  unsigned short* W2T = (unsigned short*)carve((size_t)NEXP * DMODEL * FDIM * 2);
  unsigned short* H   = (unsigned short*)carve((size_t)NROWS * FDIM * 2);
  unsigned short* ys  = (unsigned short*)carve((size_t)NROWS * DMODEL * 2);
  int*   sel          = (int*)carve((size_t)NROWS * 4);
  float* wts          = (float*)carve((size_t)NROWS * 4);
  int*   token_list   = (int*)carve((size_t)(NROWS + 256) * 4);
  int*   slot_list    = (int*)carve((size_t)(NROWS + 256) * 4);
  int*   ctrl         = (int*)carve(4096);
  int* counts  = ctrl;            // 8
  int* cursors = ctrl + 8;        // 8
  int* offsets = ctrl + 16;       // 9
  int* ntiles  = ctrl + 28;       // 1
  int* t_e     = ctrl + 32;
  int* t_r     = ctrl + 32 + MAXT;
  int* t_rend  = ctrl + 32 + 2 * MAXT;

  hipMemsetAsync(counts, 0, 64, stream);  // counts + cursors

  prep_kernel<<<PREP_BLKS, 256, 0, stream>>>(
      gate_inputs, Wg, bg, sel, wts, counts,
      inputs, Xb, w1, W1T, w2, W2T);
  scan_build_kernel<<<1, 256, 0, stream>>>(counts, offsets, ntiles, t_e, t_r, t_rend);
  scatter_kernel<<<T_TOK / 256, 256, 0, stream>>>(sel, cursors, offsets, token_list, slot_list);

  hipFuncSetAttribute((const void*)gemm256_kernel<true>,
                      hipFuncAttributeMaxDynamicSharedMemorySize, 131072);
  hipFuncSetAttribute((const void*)gemm256_kernel<false>,
                      hipFuncAttributeMaxDynamicSharedMemorySize, 131072);
  // gemm1: H = gelu(X@W1+b1). grid = 8 xcd * (2 nb-sub * 80 bt)
  gemm256_kernel<true><<<8 * 2 * MAXT, 512, 131072, stream>>>(
      Xb, W1T, b1, token_list, nullptr, t_e, t_r, t_rend, ntiles, H);
  // gemm2: ys = H@W2 scatter. grid = 4 nb * 80 bt
  gemm256_kernel<false><<<4 * MAXT, 512, 131072, stream>>>(
      H, W2T, nullptr, nullptr, slot_list, t_e, t_r, t_rend, ntiles, ys);
  combine_kernel<<<(T_TOK * DMODEL / 8) / 256, 256, 0, stream>>>(ys, wts, sel, b2, out);
}

// Round 11
// 698.890 us; speedup vs baseline: 1.1992x; 1.0102x over previous
//
#include <hip/hip_runtime.h>
#include <stdint.h>

#define T_TOK 8192
#define DMODEL 1024
#define FDIM 4096
#define NEXP 8
#define NROWS 16384      // T_TOK * K
#define MAXT 80          // max 256-row tiles

// prep_kernel block ranges
#define GATE_BLKS 2048                  // T_TOK/4
#define CVT_BLKS  4096                  // T*D/8/256
#define TR1_BLKS  4096                  // (4096/128) x (1024/64) x 8
#define TR2_BLKS  4096                  // (1024/128) x (4096/64) x 8
#define PREP_BLKS (GATE_BLKS + CVT_BLKS + TR1_BLKS + TR2_BLKS)

typedef __bf16 bf16x8 __attribute__((ext_vector_type(8)));
typedef float f32x4 __attribute__((ext_vector_type(4)));
#define AS1 __attribute__((address_space(1)))
#define AS3 __attribute__((address_space(3)))

__device__ __forceinline__ unsigned short f2bf(float f) {
  union { float f; unsigned u; } v; v.f = f;
  unsigned r = v.u + 0x7fffu + ((v.u >> 16) & 1u);
  return (unsigned short)(r >> 16);
}
__device__ __forceinline__ float bflo(unsigned u) {
  union { unsigned u; float f; } v; v.u = u << 16; return v.f;
}
__device__ __forceinline__ float bfhi(unsigned u) {
  union { unsigned u; float f; } v; v.u = u & 0xffff0000u; return v.f;
}

// ---- chunked transpose: in[k][n] f32  ->  out[(kt*Ndim + n)*64 + klocal] bf16
// tile = 64 k x 128 n. Reads 512B/row segments; writes 16KB contiguous/block.
__device__ __forceinline__ void transpose_chunk_body(
    const float* __restrict__ in, unsigned short* __restrict__ out,
    int Kdim, int Ndim, int bx, int by, int bz, float (*tb)[133])
{
  size_t ebase = (size_t)bz * (size_t)Kdim * (size_t)Ndim;
  int k0 = by * 64, n0 = bx * 128;
#pragma unroll
  for (int p = 0; p < 8; ++p) {
    int item = p * 256 + threadIdx.x;      // 2048 float4 items
    int r = item >> 5, c4 = (item & 31) * 4;
    float4 v = *(const float4*)&in[ebase + (size_t)(k0 + r) * Ndim + n0 + c4];
    tb[r][c4+0] = v.x; tb[r][c4+1] = v.y; tb[r][c4+2] = v.z; tb[r][c4+3] = v.w;
  }
  __syncthreads();
#pragma unroll
  for (int q = 0; q < 4; ++q) {
    int item = q * 256 + threadIdx.x;      // 1024 items: 128 n x 8 k-octs
    int n = item >> 3, k8 = (item & 7) * 8;
    union { unsigned short u[8]; uint4 v4; } pk;
#pragma unroll
    for (int j = 0; j < 8; ++j) pk.u[j] = f2bf(tb[k8 + j][n]);
    *(uint4*)(out + ebase + ((size_t)by * Ndim + n0 + n) * 64 + k8) = pk.v4;
  }
}

// ---------------- fused prep: gate || f32->bf16 cvt || both W transposes ------
__global__ __launch_bounds__(256) void prep_kernel(
    const float* __restrict__ gx, const float* __restrict__ Wg,
    const float* __restrict__ bg, int* __restrict__ sel,
    float* __restrict__ wts, int* __restrict__ counts,
    const float* __restrict__ inputs, unsigned short* __restrict__ Xb,
    const float* __restrict__ w1, unsigned short* __restrict__ W1T,
    const float* __restrict__ w2, unsigned short* __restrict__ W2T)
{
  __shared__ float tb[64][133];
  int b = blockIdx.x;
  if (b < GATE_BLKS) {
    int t = b * 4 + (threadIdx.x >> 6);
    int lane = threadIdx.x & 63;
    const float* row = gx + (size_t)t * DMODEL;
    float acc[NEXP];
#pragma unroll
    for (int e = 0; e < NEXP; ++e) acc[e] = 0.f;
    for (int d = lane; d < DMODEL; d += 64) {
      float x = row[d];
      const float* wgr = Wg + (size_t)d * NEXP;
#pragma unroll
      for (int e = 0; e < NEXP; ++e) acc[e] += x * wgr[e];
    }
#pragma unroll
    for (int off = 32; off > 0; off >>= 1) {
#pragma unroll
      for (int e = 0; e < NEXP; ++e) acc[e] += __shfl_down(acc[e], off);
    }
    if (lane == 0) {
      float lg[NEXP];
#pragma unroll
      for (int e = 0; e < NEXP; ++e) lg[e] = acc[e] + bg[e];
      int i1 = 0; float v1 = lg[0];
#pragma unroll
      for (int e = 1; e < NEXP; ++e) if (lg[e] > v1) { v1 = lg[e]; i1 = e; }
      int i2 = -1; float v2 = -3.4e38f;
#pragma unroll
      for (int e = 0; e < NEXP; ++e) if (e != i1 && lg[e] > v2) { v2 = lg[e]; i2 = e; }
      float ez = __expf(v2 - v1);           // v2 <= v1
      float s = 1.f / (1.f + ez);
      sel[t*2] = i1; sel[t*2+1] = i2;
      wts[t*2] = s;  wts[t*2+1] = ez * s;
      atomicAdd(&counts[i1], 1);
      atomicAdd(&counts[i2], 1);
    }
  } else if (b < GATE_BLKS + CVT_BLKS) {
    int i = (b - GATE_BLKS) * 256 + threadIdx.x;
    const float4* in4 = (const float4*)inputs;
    float4 v0 = in4[(size_t)i*2], v1 = in4[(size_t)i*2 + 1];
    union { unsigned short u[8]; uint4 q; } r;
    r.u[0]=f2bf(v0.x); r.u[1]=f2bf(v0.y); r.u[2]=f2bf(v0.z); r.u[3]=f2bf(v0.w);
    r.u[4]=f2bf(v1.x); r.u[5]=f2bf(v1.y); r.u[6]=f2bf(v1.z); r.u[7]=f2bf(v1.w);
    ((uint4*)Xb)[i] = r.q;
  } else if (b < GATE_BLKS + CVT_BLKS + TR1_BLKS) {
    // w1 [E][K=1024][N=4096] -> W1Tc [E][kt=16][n=4096][64]
    int bp = b - (GATE_BLKS + CVT_BLKS);
    transpose_chunk_body(w1, W1T, DMODEL, FDIM, bp & 31, (bp >> 5) & 15, bp >> 9, tb);
  } else {
    // w2 [E][K=4096][N=1024] -> W2Tc [E][kt=64][n=1024][64]
    int bp = b - (GATE_BLKS + CVT_BLKS + TR1_BLKS);
    transpose_chunk_body(w2, W2T, FDIM, DMODEL, bp & 7, (bp >> 3) & 63, bp >> 9, tb);
  }
}

// ---------------- offsets + 256-row tile table (parallel, 1 block) ------------
__global__ __launch_bounds__(256) void scan_build_kernel(
    const int* __restrict__ counts, int* __restrict__ offsets,
    int* __restrict__ ntiles, int* __restrict__ t_e, int* __restrict__ t_r,
    int* __restrict__ t_rend)
{
  __shared__ int sc[8], soff[9], stile[9];
  int tid = threadIdx.x;
  if (tid < 8) sc[tid] = counts[tid];
  __syncthreads();
  if (tid == 0) {
    int off = 0, tl = 0;
#pragma unroll
    for (int e = 0; e < NEXP; ++e) {
      soff[e] = off; stile[e] = tl;
      off += sc[e];
      tl += (sc[e] + 255) >> 8;
    }
    soff[8] = off; stile[8] = tl;
  }
  __syncthreads();
  int ntot = stile[8];
  for (int idx = tid; idx < ntot; idx += 256) {
    int e = 0;
#pragma unroll
    for (int q = 0; q < NEXP; ++q) if (idx >= stile[q + 1]) e = q + 1;
    int r = (idx - stile[e]) * 256;
    t_e[idx] = e; t_r[idx] = soff[e] + r; t_rend[idx] = soff[e] + sc[e];
  }
  if (tid < 9) offsets[tid] = soff[tid];
  if (tid == 0) *ntiles = ntot;
}

// ---------------- scatter: wave-aggregated per-expert atomics -----------------
__global__ __launch_bounds__(256) void scatter_kernel(
    const int* __restrict__ sel, int* __restrict__ cursors,
    const int* __restrict__ offsets, int* __restrict__ token_list,
    int* __restrict__ slot_list)
{
  int t = blockIdx.x * 256 + threadIdx.x;
  int lane = threadIdx.x & 63;
  unsigned long long ltmask = (lane == 63) ? 0x7fffffffffffffffull
                                           : ((1ull << lane) - 1ull);
#pragma unroll
  for (int k = 0; k < 2; ++k) {
    int e = sel[t*2 + k];
#pragma unroll
    for (int ex = 0; ex < NEXP; ++ex) {
      unsigned long long m = __ballot(e == ex);
      if (m == 0ull) continue;
      if (e == ex) {
        int leader = __ffsll((unsigned long long)m) - 1;
        int cnt = __popcll(m);
        int base = 0;
        if (lane == leader) base = atomicAdd(&cursors[ex], cnt);
        base = __shfl(base, leader);
        int r = offsets[ex] + base + __popcll(m & ltmask);
        token_list[r] = t;
        slot_list[r] = t*2 + k;
      }
    }
  }
}

// ---------------- grouped GEMM 256x256, BK=64, 4-phase counted-vmcnt ----------
// Schedule unchanged from R9 (verified). B now read from the k-chunked layout
// [e][kt][n][64]: stage source = eB + kt*NOUT*64 + (n0+m)*64 + ch*8 — each
// half-tile stage reads a contiguous 32KB region.
template<bool G1>
__global__ __launch_bounds__(512, 2) void gemm256_kernel(
    const unsigned short* __restrict__ A, const unsigned short* __restrict__ B,
    const float* __restrict__ b1, const int* __restrict__ token_list,
    const int* __restrict__ slot_list,
    const int* __restrict__ tile_e, const int* __restrict__ tile_r,
    const int* __restrict__ tile_rend, const int* __restrict__ ntiles,
    unsigned short* __restrict__ outp)
{
  constexpr int KDIM = G1 ? DMODEL : FDIM;   // K extent
  constexpr int NKT  = KDIM / 64;
  constexpr int NOUT = G1 ? FDIM : DMODEL;   // output row width
  constexpr int KTB  = NOUT * 64;            // B k-tile stride (elements)

  int bid = blockIdx.x;
  int nb, bt;
  if constexpr (G1) {                        // 16 nb-panels: pin 2 per XCD, bt-major
    int xcd = bid & 7, idx = bid >> 3;
    nb = xcd * 2 + (idx & 1);
    bt = idx >> 1;
  } else {                                   // 4 nb-panels, bt-major
    nb = bid & 3;
    bt = bid >> 2;
  }
  if (bt >= *ntiles) return;
  const int e = tile_e[bt], row0 = tile_r[bt], rend = tile_rend[bt];
  const int n0 = nb * 256;

  const int tid = threadIdx.x, lane = tid & 63, wave = tid >> 6;
  extern __shared__ __align__(16) char smem[];   // 131072 B

  const int lr8 = lane >> 3, g8 = lane & 7, ch = g8 ^ lr8;

  int mA[2], mB[2];
#pragma unroll
  for (int p = 0; p < 2; ++p)
    mA[p] = (wave < 4) ? (p*64 + wave*16) : (128 + p*64 + (wave-4)*16);
#pragma unroll
  for (int nh = 0; nh < 2; ++nh)
    mB[nh] = (wave >> 1)*64 + nh*32 + (wave & 1)*16;

  const unsigned short* eB = B + (size_t)e * KDIM * NOUT;
  unsigned aoffs[2][2], boffs[2][2];
#pragma unroll
  for (int p = 0; p < 2; ++p)
#pragma unroll
    for (int l = 0; l < 2; ++l) {
      int m = mA[p] + l*8 + lr8;
      int row = row0 + m; if (row > NROWS - 1) row = NROWS - 1;
      int arow = G1 ? token_list[row] : row;
      aoffs[p][l] = (unsigned)arow * KDIM + ch*8;
      int mb = mB[p] + l*8 + lr8;
      boffs[p][l] = (unsigned)((n0 + mb) * 64 + ch*8);
    }

  auto stage_half = [&](int p, int ktn, int bsel) {
    char* base = smem + bsel * 65536;
    if (p < 2) {
      const int kb = ktn * 64;
#pragma unroll
      for (int l = 0; l < 2; ++l)
        __builtin_amdgcn_global_load_lds(
            (const AS1 void*)(A + aoffs[p][l] + kb),
            (AS3 void*)(base + ((mA[p] + l*8) << 7)), 16, 0, 0);
    } else {
      const int nh = p - 2;
      const unsigned short* bk = eB + (size_t)ktn * KTB;
#pragma unroll
      for (int l = 0; l < 2; ++l)
        __builtin_amdgcn_global_load_lds(
            (const AS1 void*)(bk + boffs[nh][l]),
            (AS3 void*)(base + 32768 + ((mB[nh] + l*8) << 7)), 16, 0, 0);
    }
  };

  f32x4 acc[8][4] = {};
  bf16x8 aR[4][2];        // current A-half: 4 row-frags x 2 k-slices
  bf16x8 bR[2][2][2];     // both B-halves: [nh][jj][ks]
  const int wr = wave >> 2, wc = wave & 3;
  const int lm = lane & 15, lk = lane >> 4, l7 = lane & 7;
  const unsigned abase = (unsigned)(wr*128 + lm) * 128;
  const unsigned bbase = 32768u + (unsigned)(wc*64 + lm) * 128;
  const unsigned kx0 = (unsigned)((lk ^ l7) << 4);
  const unsigned kx1 = (unsigned)(((4 + lk) ^ l7) << 4);

  auto rdA = [&](const char* base, int mh) {
#pragma unroll
    for (int i = 0; i < 4; ++i) {
      const char* pA = base + abase + mh*8192 + i*2048;
      aR[i][0] = *(const bf16x8*)(pA + kx0);
      aR[i][1] = *(const bf16x8*)(pA + kx1);
    }
  };
  auto rdB = [&](const char* base, int nh) {
#pragma unroll
    for (int jj = 0; jj < 2; ++jj) {
      const char* pB = base + bbase + nh*4096 + jj*2048;
      bR[nh][jj][0] = *(const bf16x8*)(pB + kx0);
      bR[nh][jj][1] = *(const bf16x8*)(pB + kx1);
    }
  };
  auto mm = [&](int mh, int nh) {
    __builtin_amdgcn_s_setprio(1);
#pragma unroll
    for (int i = 0; i < 4; ++i)
#pragma unroll
      for (int jj = 0; jj < 2; ++jj) {
        acc[mh*4+i][nh*2+jj] = __builtin_amdgcn_mfma_f32_16x16x32_bf16(
            aR[i][0], bR[nh][jj][0], acc[mh*4+i][nh*2+jj], 0, 0, 0);
        acc[mh*4+i][nh*2+jj] = __builtin_amdgcn_mfma_f32_16x16x32_bf16(
            aR[i][1], bR[nh][jj][1], acc[mh*4+i][nh*2+jj], 0, 0, 0);
      }
    __builtin_amdgcn_s_setprio(0);
  };

  // prologue: stage tile 0 halves in consumption order A0,B0,B1,A1
  stage_half(0, 0, 0);
  stage_half(2, 0, 0);
  stage_half(3, 0, 0);
  stage_half(1, 0, 0);

  for (int kt = 0; kt < NKT; ++kt) {
    const int b = kt & 1;
    const int nxt = b ^ 1;
    const char* base = smem + b * 65536;
    const bool pre = (kt + 1 < NKT);
    // ---- P0: quad (0,0); needs A0,B0 ----
    if (pre) {
      stage_half(0, kt + 1, nxt);
      asm volatile("s_waitcnt vmcnt(6)" ::: "memory");
    } else {
      asm volatile("s_waitcnt vmcnt(4)" ::: "memory");
    }
    __builtin_amdgcn_s_barrier();
    __builtin_amdgcn_sched_barrier(0);
    rdA(base, 0); rdB(base, 0);
    asm volatile("s_waitcnt lgkmcnt(0)" ::: "memory");
    __builtin_amdgcn_sched_barrier(0);
    mm(0, 0);
    __builtin_amdgcn_s_barrier();
    // ---- P1: quad (0,1); needs B1 ----
    if (pre) {
      stage_half(2, kt + 1, nxt);
      asm volatile("s_waitcnt vmcnt(6)" ::: "memory");
    } else {
      asm volatile("s_waitcnt vmcnt(2)" ::: "memory");
    }
    __builtin_amdgcn_s_barrier();
    __builtin_amdgcn_sched_barrier(0);
    rdB(base, 1);
    asm volatile("s_waitcnt lgkmcnt(0)" ::: "memory");
    __builtin_amdgcn_sched_barrier(0);
    mm(0, 1);
    __builtin_amdgcn_s_barrier();
    // ---- P2: quad (1,1); needs A1 ----
    if (pre) {
      stage_half(3, kt + 1, nxt);
      asm volatile("s_waitcnt vmcnt(6)" ::: "memory");
    } else {
      asm volatile("s_waitcnt vmcnt(0)" ::: "memory");
    }
    __builtin_amdgcn_s_barrier();
    __builtin_amdgcn_sched_barrier(0);
    rdA(base, 1);
    asm volatile("s_waitcnt lgkmcnt(0)" ::: "memory");
    __builtin_amdgcn_sched_barrier(0);
    mm(1, 1);
    __builtin_amdgcn_s_barrier();
    // ---- P3: quad (1,0); no reads ----
    if (pre) stage_half(1, kt + 1, nxt);
    mm(1, 0);
    __builtin_amdgcn_s_barrier();
    __builtin_amdgcn_sched_barrier(0);
  }

  asm volatile("" ::: "memory");
  float bias[4] = {};
  if constexpr (G1) {
#pragma unroll
    for (int j = 0; j < 4; ++j) bias[j] = b1[(size_t)e * FDIM + n0 + wc*64 + j*16 + lm];
  }

  // epilogue: 8 chunks of 32 rows; [gelu] -> f32 LDS (stride 260) -> bf16 x8
  float* eps = (float*)smem;
#pragma unroll
  for (int c = 0; c < 8; ++c) {
    __syncthreads();
    if (wr == (c >> 2)) {
#pragma unroll
      for (int ii = 0; ii < 2; ++ii) {
        const int mi = (c & 3) * 2 + ii;
#pragma unroll
        for (int j = 0; j < 4; ++j) {
#pragma unroll
          for (int r = 0; r < 4; ++r) {
            float v = acc[mi][j][r];
            if constexpr (G1) {
              v += bias[j];
              float z2 = 1.5957691216f * (v + 0.044715f * v * v * v);
              v = v / (1.f + __expf(-z2));
            }
            eps[(ii*16 + lk*4 + r) * 260 + wc*64 + j*16 + lm] = v;
          }
        }
      }
    }
    __syncthreads();
#pragma unroll
    for (int u = 0; u < 2; ++u) {
      int item = u * 512 + tid;               // 1024 items: 32 rows x 32 octs
      int lrow = item >> 5, c8 = (item & 31) * 8;
      int gr = row0 + c * 32 + lrow;
      if (gr < rend) {
        float4 v0 = *(const float4*)&eps[lrow * 260 + c8];
        float4 v1 = *(const float4*)&eps[lrow * 260 + c8 + 4];
        union { unsigned short u[8]; uint4 q; } pk;
        pk.u[0]=f2bf(v0.x); pk.u[1]=f2bf(v0.y); pk.u[2]=f2bf(v0.z); pk.u[3]=f2bf(v0.w);
        pk.u[4]=f2bf(v1.x); pk.u[5]=f2bf(v1.y); pk.u[6]=f2bf(v1.z); pk.u[7]=f2bf(v1.w);
        size_t orow;
        if constexpr (G1) orow = (size_t)gr * FDIM;
        else              orow = (size_t)slot_list[gr] * DMODEL;
        *(uint4*)(outp + orow + n0 + c8) = pk.q;
      }
    }
  }
}

// ---------------- combine: out = sum_k w_k*(y_k + b2[e_k]) --------------------
__global__ __launch_bounds__(256) void combine_kernel(
    const unsigned short* __restrict__ ys, const float* __restrict__ wts,
    const int* __restrict__ sel, const float* __restrict__ b2,
    float* __restrict__ out)
{
  int i = blockIdx.x * 256 + threadIdx.x;   // over T*D/8
  int t = i >> 7, d8 = i & 127;
  float w0 = wts[t*2], w1 = wts[t*2 + 1];
  int e0 = sel[t*2], e1 = sel[t*2 + 1];
  const uint4* ys4 = (const uint4*)ys;
  uint4 ya = ys4[(size_t)(t*2) * 128 + d8];
  uint4 yb = ys4[(size_t)(t*2 + 1) * 128 + d8];
  const float4* b24 = (const float4*)b2;
  float4 c0a = b24[e0*256 + d8*2], c0b = b24[e0*256 + d8*2 + 1];
  float4 c1a = b24[e1*256 + d8*2], c1b = b24[e1*256 + d8*2 + 1];
  float4 o0, o1;
  o0.x = w0*(bflo(ya.x)+c0a.x) + w1*(bflo(yb.x)+c1a.x);
  o0.y = w0*(bfhi(ya.x)+c0a.y) + w1*(bfhi(yb.x)+c1a.y);
  o0.z = w0*(bflo(ya.y)+c0a.z) + w1*(bflo(yb.y)+c1a.z);
  o0.w = w0*(bfhi(ya.y)+c0a.w) + w1*(bfhi(yb.y)+c1a.w);
  o1.x = w0*(bflo(ya.z)+c0b.x) + w1*(bflo(yb.z)+c1b.x);
  o1.y = w0*(bfhi(ya.z)+c0b.y) + w1*(bfhi(yb.z)+c1b.y);
  o1.z = w0*(bflo(ya.w)+c0b.z) + w1*(bflo(yb.w)+c1b.z);
  o1.w = w0*(bfhi(ya.w)+c0b.w) + w1*(bfhi(yb.w)+c1b.w);
  float4* out4 = (float4*)out;
  out4[(size_t)t * 256 + d8*2]     = o0;
  out4[(size_t)t * 256 + d8*2 + 1] = o1;
}

// ---------------- host ---------------------------------------------------------
extern "C" void kernel_launch(void* const* d_in, const int* in_sizes, int n_in,
                              void* d_out, int out_size, void* d_ws, size_t ws_size,
                              hipStream_t stream)
{
  const float* gate_inputs = (const float*)d_in[0];
  const float* inputs      = (const float*)d_in[1];
  const float* Wg          = (const float*)d_in[2];
  const float* bg          = (const float*)d_in[3];
  const float* w1          = (const float*)d_in[4];
  const float* b1          = (const float*)d_in[5];
  const float* w2          = (const float*)d_in[6];
  const float* b2          = (const float*)d_in[7];
  float* out = (float*)d_out;

  char* ws = (char*)d_ws;
  size_t o = 0;
  auto carve = [&](size_t bytes) { void* p = ws + o; o += (bytes + 255) & ~(size_t)255; return p; };
  unsigned short* Xb  = (unsigned short*)carve((size_t)T_TOK * DMODEL * 2);
  unsigned short* W1T = (unsigned short*)carve((size_t)NEXP * FDIM * DMODEL * 2);
  unsigned short* W2T = (unsigned short*)carve((size_t)NEXP * DMODEL * FDIM * 2);
  unsigned short* H   = (unsigned short*)carve((size_t)NROWS * FDIM * 2);
  unsigned short* ys  = (unsigned short*)carve((size_t)NROWS * DMODEL * 2);
  int*   sel          = (int*)carve((size_t)NROWS * 4);
  float* wts          = (float*)carve((size_t)NROWS * 4);
  int*   token_list   = (int*)carve((size_t)(NROWS + 256) * 4);
  int*   slot_list    = (int*)carve((size_t)(NROWS + 256) * 4);
  int*   ctrl         = (int*)carve(4096);
  int* counts  = ctrl;            // 8
  int* cursors = ctrl + 8;        // 8
  int* offsets = ctrl + 16;       // 9
  int* ntiles  = ctrl + 28;       // 1
  int* t_e     = ctrl + 32;
  int* t_r     = ctrl + 32 + MAXT;
  int* t_rend  = ctrl + 32 + 2 * MAXT;

  hipMemsetAsync(counts, 0, 64, stream);  // counts + cursors

  prep_kernel<<<PREP_BLKS, 256, 0, stream>>>(
      gate_inputs, Wg, bg, sel, wts, counts,
      inputs, Xb, w1, W1T, w2, W2T);
  scan_build_kernel<<<1, 256, 0, stream>>>(counts, offsets, ntiles, t_e, t_r, t_rend);
  scatter_kernel<<<T_TOK / 256, 256, 0, stream>>>(sel, cursors, offsets, token_list, slot_list);

  hipFuncSetAttribute((const void*)gemm256_kernel<true>,
                      hipFuncAttributeMaxDynamicSharedMemorySize, 131072);
  hipFuncSetAttribute((const void*)gemm256_kernel<false>,
                      hipFuncAttributeMaxDynamicSharedMemorySize, 131072);
  // gemm1: H = gelu(X@W1+b1). grid = 8 xcd * (2 nb-sub * 80 bt)
  gemm256_kernel<true><<<8 * 2 * MAXT, 512, 131072, stream>>>(
      Xb, W1T, b1, token_list, nullptr, t_e, t_r, t_rend, ntiles, H);
  // gemm2: ys = H@W2 scatter. grid = 4 nb * 80 bt
  gemm256_kernel<false><<<4 * MAXT, 512, 131072, stream>>>(
      H, W2T, nullptr, nullptr, slot_list, t_e, t_r, t_rend, ntiles, ys);
  combine_kernel<<<(T_TOK * DMODEL / 8) / 256, 256, 0, stream>>>(ys, wts, sel, b2, out);
}